// Round 1
// baseline (635.763 us; speedup 1.0000x reference)
//
#include <hip/hip_runtime.h>

static constexpr int F_IN  = 128;
static constexpr int F_H   = 64;
static constexpr int F_OUT = 10;

// ---------------------------------------------------------------- detect/convert
// edge_index may arrive as int64 (reference dtype) or int32 (JAX default
// demotion). Detect on-device: if the high 32 bits of the first 64 u64 words
// are all zero, it's int64 (values < 100000); random int32 pairs make that
// essentially impossible.
__global__ __launch_bounds__(64) void k_detect(const unsigned long long* __restrict__ u,
                                               int* __restrict__ flag) {
    unsigned long long v = u[threadIdx.x];
    int hz = ((v >> 32) == 0ull) ? 1 : 0;
    int all64 = __all(hz);
    if (threadIdx.x == 0) flag[0] = all64;
}

__global__ __launch_bounds__(256) void k_convert(const void* __restrict__ ein,
                                                 const int* __restrict__ flag,
                                                 int* __restrict__ out, int n) {
    int i = blockIdx.x * 256 + threadIdx.x;
    if (i >= n) return;
    if (flag[0]) out[i] = (int)((const long long*)ein)[i];
    else         out[i] = ((const int*)ein)[i];
}

// ---------------------------------------------------------------- degree + hist
__global__ __launch_bounds__(256) void k_deg(const int* __restrict__ dst,
                                             const float* __restrict__ ew,
                                             float* __restrict__ deg,
                                             int* __restrict__ cnt, int E) {
    int e = blockIdx.x * 256 + threadIdx.x;
    if (e >= E) return;
    int d = dst[e];
    atomicAdd(&deg[d], ew[e]);
    atomicAdd(&cnt[d], 1);
}

__global__ __launch_bounds__(256) void k_dinv(float* __restrict__ deg, int N) {
    int i = blockIdx.x * 256 + threadIdx.x;
    if (i >= N) return;
    deg[i] = rsqrtf(deg[i] + 1.0f);   // deg includes self-loop weight 1
}

// ---------------------------------------------------------------- 3-pass scan (row_ptr)
__global__ __launch_bounds__(256) void k_scanA(const int* __restrict__ cnt,
                                               int* __restrict__ bsum, int N) {
    int gid = blockIdx.x * 256 + threadIdx.x;
    int s = 0;
#pragma unroll
    for (int j = 0; j < 4; ++j) {
        int i = gid * 4 + j;
        if (i < N) s += cnt[i];
    }
    __shared__ int sm[256];
    sm[threadIdx.x] = s;
    __syncthreads();
    for (int off = 128; off > 0; off >>= 1) {
        if (threadIdx.x < off) sm[threadIdx.x] += sm[threadIdx.x + off];
        __syncthreads();
    }
    if (threadIdx.x == 0) bsum[blockIdx.x] = sm[0];
}

__global__ void k_scanB(int* __restrict__ bsum, int nb) {
    if (threadIdx.x == 0 && blockIdx.x == 0) {
        int acc = 0;
        for (int i = 0; i < nb; ++i) { int v = bsum[i]; bsum[i] = acc; acc += v; }
    }
}

__global__ __launch_bounds__(256) void k_scanC(const int* __restrict__ cnt,
                                               const int* __restrict__ bsum,
                                               int* __restrict__ rp, int N, int E) {
    int tid = threadIdx.x;
    int gid = blockIdx.x * 256 + tid;
    int c[4]; int s = 0;
#pragma unroll
    for (int j = 0; j < 4; ++j) {
        int i = gid * 4 + j;
        c[j] = (i < N) ? cnt[i] : 0;
        s += c[j];
    }
    __shared__ int sm[256];
    sm[tid] = s;
    __syncthreads();
    for (int off = 1; off < 256; off <<= 1) {
        int v = 0;
        if (tid >= off) v = sm[tid - off];
        __syncthreads();
        sm[tid] += v;
        __syncthreads();
    }
    int run = bsum[blockIdx.x] + (sm[tid] - s);   // exclusive base for this thread
#pragma unroll
    for (int j = 0; j < 4; ++j) {
        int i = gid * 4 + j;
        if (i < N) rp[i] = run;
        run += c[j];
    }
    if (gid == 0) rp[N] = E;
}

// ---------------------------------------------------------------- CSR scatter
__global__ __launch_bounds__(256) void k_scatter(const int* __restrict__ src,
                                                 const int* __restrict__ dst,
                                                 const float* __restrict__ ew,
                                                 const float* __restrict__ dinv,
                                                 const int* __restrict__ rp,
                                                 int* __restrict__ cur,
                                                 int* __restrict__ col,
                                                 float* __restrict__ val, int E) {
    int e = blockIdx.x * 256 + threadIdx.x;
    if (e >= E) return;
    int s = src[e], d = dst[e];
    float nv = dinv[s] * ew[e] * dinv[d];
    int p = rp[d] + atomicAdd(&cur[d], 1);
    col[p] = s;
    val[p] = nv;
}

// ---------------------------------------------------------------- GEMM: [M,K]@[K,64]
// block = 256 threads (16x16), 64-row x 64-col tile, 4x4 per thread, K staged
// in 64-wide chunks. As padded to 68 -> 2-way LDS conflicts only (free).
template <int K>
__global__ __launch_bounds__(256) void k_gemm(const float* __restrict__ A,
                                              const float* __restrict__ W,
                                              float* __restrict__ C, int M) {
    __shared__ float As[64][68];
    __shared__ float Ws[64][64];
    int tid = threadIdx.x;
    int tx = tid & 15, ty = tid >> 4;
    int rb = blockIdx.x * 64;
    float acc[4][4] = {};
    for (int kc = 0; kc < K; kc += 64) {
        __syncthreads();   // protect previous iteration's LDS reads
        for (int e = tid * 4; e < 64 * 64; e += 1024) {
            int r = e >> 6, k = e & 63;
            int gr = rb + r;
            float4 v = make_float4(0.f, 0.f, 0.f, 0.f);
            if (gr < M) v = *(const float4*)&A[(long)gr * K + kc + k];
            *(float4*)&As[r][k] = v;
        }
        for (int e = tid * 4; e < 64 * 64; e += 1024) {
            int r = e >> 6, k = e & 63;
            *(float4*)&Ws[r][k] = *(const float4*)&W[(long)(kc + r) * 64 + k];
        }
        __syncthreads();
#pragma unroll 16
        for (int k = 0; k < 64; ++k) {
            float a0 = As[ty * 4 + 0][k];
            float a1 = As[ty * 4 + 1][k];
            float a2 = As[ty * 4 + 2][k];
            float a3 = As[ty * 4 + 3][k];
            float4 b = *(float4*)&Ws[k][tx * 4];
            acc[0][0] = fmaf(a0, b.x, acc[0][0]); acc[0][1] = fmaf(a0, b.y, acc[0][1]);
            acc[0][2] = fmaf(a0, b.z, acc[0][2]); acc[0][3] = fmaf(a0, b.w, acc[0][3]);
            acc[1][0] = fmaf(a1, b.x, acc[1][0]); acc[1][1] = fmaf(a1, b.y, acc[1][1]);
            acc[1][2] = fmaf(a1, b.z, acc[1][2]); acc[1][3] = fmaf(a1, b.w, acc[1][3]);
            acc[2][0] = fmaf(a2, b.x, acc[2][0]); acc[2][1] = fmaf(a2, b.y, acc[2][1]);
            acc[2][2] = fmaf(a2, b.z, acc[2][2]); acc[2][3] = fmaf(a2, b.w, acc[2][3]);
            acc[3][0] = fmaf(a3, b.x, acc[3][0]); acc[3][1] = fmaf(a3, b.y, acc[3][1]);
            acc[3][2] = fmaf(a3, b.z, acc[3][2]); acc[3][3] = fmaf(a3, b.w, acc[3][3]);
        }
    }
#pragma unroll
    for (int j = 0; j < 4; ++j) {
        int gr = rb + ty * 4 + j;
        if (gr < M) {
            float4 v = make_float4(acc[j][0], acc[j][1], acc[j][2], acc[j][3]);
            *(float4*)&C[(long)gr * 64 + tx * 4] = v;
        }
    }
}

// ---------------------------------------------------------------- aggregation
// one wave per node, lane = feature. acc = h[i]*dinv[i]^2 (self loop) + bias,
// then gather-sum norm_e * h[src_e]. ReLU fused (both GCN layers use it).
__global__ __launch_bounds__(256) void k_agg(const float* __restrict__ h,
                                             const int* __restrict__ rp,
                                             const int* __restrict__ col,
                                             const float* __restrict__ val,
                                             const float* __restrict__ dinv,
                                             const float* __restrict__ bias,
                                             float* __restrict__ out, int N) {
    int wid  = (blockIdx.x * 256 + threadIdx.x) >> 6;
    int lane = threadIdx.x & 63;
    if (wid >= N) return;
    float di  = dinv[wid];
    float acc = fmaf(h[(long)wid * 64 + lane], di * di, bias[lane]);
    int e0 = rp[wid], e1 = rp[wid + 1];
    for (int e = e0; e < e1; ++e) {
        int   s = col[e];
        float w = val[e];
        acc = fmaf(w, h[(long)s * 64 + lane], acc);
    }
    out[(long)wid * 64 + lane] = fmaxf(acc, 0.0f);
}

// ---------------------------------------------------------------- FC: [M,64]@[64,10]+b
__global__ __launch_bounds__(256) void k_fc(const float* __restrict__ h,
                                            const float* __restrict__ W,
                                            const float* __restrict__ b,
                                            float* __restrict__ out, int N) {
    __shared__ float Ws[64 * 10];
    __shared__ float bs[16];
    int tid = threadIdx.x;
    for (int e = tid; e < 64 * 10; e += 256) Ws[e] = W[e];
    if (tid < 10) bs[tid] = b[tid];
    __syncthreads();
    int i = blockIdx.x * 256 + tid;
    if (i >= N) return;
    float acc[10];
#pragma unroll
    for (int j = 0; j < 10; ++j) acc[j] = bs[j];
    const float4* row = (const float4*)&h[(long)i * 64];
#pragma unroll
    for (int c = 0; c < 16; ++c) {
        float4 a = row[c];
#pragma unroll
        for (int j = 0; j < 10; ++j) {
            acc[j] = fmaf(a.x, Ws[(4 * c + 0) * 10 + j], acc[j]);
            acc[j] = fmaf(a.y, Ws[(4 * c + 1) * 10 + j], acc[j]);
            acc[j] = fmaf(a.z, Ws[(4 * c + 2) * 10 + j], acc[j]);
            acc[j] = fmaf(a.w, Ws[(4 * c + 3) * 10 + j], acc[j]);
        }
    }
#pragma unroll
    for (int j = 0; j < 10; ++j) out[(long)i * 10 + j] = acc[j];
}

// ---------------------------------------------------------------- launch
extern "C" void kernel_launch(void* const* d_in, const int* in_sizes, int n_in,
                              void* d_out, int out_size, void* d_ws, size_t ws_size,
                              hipStream_t stream) {
    const float* x    = (const float*)d_in[0];
    const void*  eidx = d_in[1];
    const float* ew   = (const float*)d_in[2];
    const float* W1   = (const float*)d_in[3];
    const float* b1   = (const float*)d_in[4];
    const float* W2   = (const float*)d_in[5];
    const float* b2   = (const float*)d_in[6];
    const float* Wfc  = (const float*)d_in[7];
    const float* bfc  = (const float*)d_in[8];
    float* out = (float*)d_out;

    const int N = in_sizes[0] / F_IN;   // 100000
    const int E = in_sizes[2];          // 1600000

    char* w = (char*)d_ws;
    size_t off = 0;
    auto alloc = [&](size_t bytes) {
        void* p = w + off;
        off += (bytes + 255) & ~(size_t)255;
        return p;
    };
    float* dinv = (float*)alloc((size_t)N * 4);        // deg, then rsqrt in-place
    int*   cnt  = (int*)alloc((size_t)N * 4);
    int*   rp   = (int*)alloc((size_t)(N + 1) * 4);
    int*   cur  = (int*)alloc((size_t)N * 4);
    int*   bsum = (int*)alloc(4096);
    int*   flag = (int*)alloc(256);
    int*   conv = (int*)alloc((size_t)2 * E * 4);      // src | dst as int32
    int*   col  = (int*)alloc((size_t)E * 4);
    float* val  = (float*)alloc((size_t)E * 4);
    float* h1   = (float*)alloc((size_t)N * F_H * 4);
    float* g    = (float*)alloc((size_t)N * F_H * 4);
    (void)ws_size;

    hipMemsetAsync(dinv, 0, (size_t)N * 4, stream);
    hipMemsetAsync(cnt,  0, (size_t)N * 4, stream);
    hipMemsetAsync(cur,  0, (size_t)N * 4, stream);

    const int NB = (N + 1023) / 1024;   // scan blocks (256 thr x 4 elem)

    k_detect<<<1, 64, 0, stream>>>((const unsigned long long*)eidx, flag);
    k_convert<<<(2 * E + 255) / 256, 256, 0, stream>>>(eidx, flag, conv, 2 * E);
    k_deg<<<(E + 255) / 256, 256, 0, stream>>>(conv + E, ew, dinv, cnt, E);
    k_dinv<<<(N + 255) / 256, 256, 0, stream>>>(dinv, N);
    k_scanA<<<NB, 256, 0, stream>>>(cnt, bsum, N);
    k_scanB<<<1, 64, 0, stream>>>(bsum, NB);
    k_scanC<<<NB, 256, 0, stream>>>(cnt, bsum, rp, N, E);
    k_scatter<<<(E + 255) / 256, 256, 0, stream>>>(conv, conv + E, ew, dinv, rp, cur,
                                                   col, val, E);

    const int GB = (N + 63) / 64;       // gemm row-tiles
    k_gemm<F_IN><<<GB, 256, 0, stream>>>(x, W1, h1, N);                 // h1 = x@W1
    k_agg<<<(N + 3) / 4, 256, 0, stream>>>(h1, rp, col, val, dinv, b1, g, N);
    k_gemm<F_H><<<GB, 256, 0, stream>>>(g, W2, h1, N);                  // h2pre = g@W2
    k_agg<<<(N + 3) / 4, 256, 0, stream>>>(h1, rp, col, val, dinv, b2, g, N);
    k_fc<<<(N + 255) / 256, 256, 0, stream>>>(g, Wfc, bfc, out, N);
}

// Round 2
// 453.100 us; speedup vs baseline: 1.4031x; 1.4031x over previous
//
#include <hip/hip_runtime.h>

static constexpr int F_IN  = 128;
static constexpr int F_H   = 64;
static constexpr int F_OUT = 10;

// ---------------------------------------------------------------- detect/convert
// edge_index may arrive as int64 (reference dtype) or int32 (JAX default
// demotion). Detect on-device: if the high 32 bits of the first 64 u64 words
// are all zero, it's int64 (values < 100000); random int32 pairs make that
// essentially impossible.
__global__ __launch_bounds__(64) void k_detect(const unsigned long long* __restrict__ u,
                                               int* __restrict__ flag) {
    unsigned long long v = u[threadIdx.x];
    int hz = ((v >> 32) == 0ull) ? 1 : 0;
    int all64 = __all(hz);
    if (threadIdx.x == 0) flag[0] = all64;
}

__global__ __launch_bounds__(256) void k_convert(const void* __restrict__ ein,
                                                 const int* __restrict__ flag,
                                                 int* __restrict__ out, int n) {
    int i = blockIdx.x * 256 + threadIdx.x;
    if (i >= n) return;
    if (flag[0]) out[i] = (int)((const long long*)ein)[i];
    else         out[i] = ((const int*)ein)[i];
}

// ---------------------------------------------------------------- degree + hist
__global__ __launch_bounds__(256) void k_deg(const int* __restrict__ dst,
                                             const float* __restrict__ ew,
                                             float* __restrict__ deg,
                                             int* __restrict__ cnt, int E) {
    int e = blockIdx.x * 256 + threadIdx.x;
    if (e >= E) return;
    int d = dst[e];
    atomicAdd(&deg[d], ew[e]);
    atomicAdd(&cnt[d], 1);
}

__global__ __launch_bounds__(256) void k_dinv(float* __restrict__ deg, int N) {
    int i = blockIdx.x * 256 + threadIdx.x;
    if (i >= N) return;
    deg[i] = rsqrtf(deg[i] + 1.0f);   // deg includes self-loop weight 1
}

// ---------------------------------------------------------------- 3-pass scan (row_ptr)
__global__ __launch_bounds__(256) void k_scanA(const int* __restrict__ cnt,
                                               int* __restrict__ bsum, int N) {
    int gid = blockIdx.x * 256 + threadIdx.x;
    int s = 0;
#pragma unroll
    for (int j = 0; j < 4; ++j) {
        int i = gid * 4 + j;
        if (i < N) s += cnt[i];
    }
    __shared__ int sm[256];
    sm[threadIdx.x] = s;
    __syncthreads();
    for (int off = 128; off > 0; off >>= 1) {
        if (threadIdx.x < off) sm[threadIdx.x] += sm[threadIdx.x + off];
        __syncthreads();
    }
    if (threadIdx.x == 0) bsum[blockIdx.x] = sm[0];
}

__global__ void k_scanB(int* __restrict__ bsum, int nb) {
    if (threadIdx.x == 0 && blockIdx.x == 0) {
        int acc = 0;
        for (int i = 0; i < nb; ++i) { int v = bsum[i]; bsum[i] = acc; acc += v; }
    }
}

__global__ __launch_bounds__(256) void k_scanC(const int* __restrict__ cnt,
                                               const int* __restrict__ bsum,
                                               int* __restrict__ rp, int N, int E) {
    int tid = threadIdx.x;
    int gid = blockIdx.x * 256 + tid;
    int c[4]; int s = 0;
#pragma unroll
    for (int j = 0; j < 4; ++j) {
        int i = gid * 4 + j;
        c[j] = (i < N) ? cnt[i] : 0;
        s += c[j];
    }
    __shared__ int sm[256];
    sm[tid] = s;
    __syncthreads();
    for (int off = 1; off < 256; off <<= 1) {
        int v = 0;
        if (tid >= off) v = sm[tid - off];
        __syncthreads();
        sm[tid] += v;
        __syncthreads();
    }
    int run = bsum[blockIdx.x] + (sm[tid] - s);   // exclusive base for this thread
#pragma unroll
    for (int j = 0; j < 4; ++j) {
        int i = gid * 4 + j;
        if (i < N) rp[i] = run;
        run += c[j];
    }
    if (gid == 0) rp[N] = E;
}

// ---------------------------------------------------------------- CSR scatter
__global__ __launch_bounds__(256) void k_scatter(const int* __restrict__ src,
                                                 const int* __restrict__ dst,
                                                 const float* __restrict__ ew,
                                                 const float* __restrict__ dinv,
                                                 const int* __restrict__ rp,
                                                 int* __restrict__ cur,
                                                 int* __restrict__ col,
                                                 float* __restrict__ val, int E) {
    int e = blockIdx.x * 256 + threadIdx.x;
    if (e >= E) return;
    int s = src[e], d = dst[e];
    float nv = dinv[s] * ew[e] * dinv[d];
    int p = rp[d] + atomicAdd(&cur[d], 1);
    col[p] = s;
    val[p] = nv;
}

// ---------------------------------------------------------------- GEMM: [M,K]@[K,64]
template <int K>
__global__ __launch_bounds__(256) void k_gemm(const float* __restrict__ A,
                                              const float* __restrict__ W,
                                              float* __restrict__ C, int M) {
    __shared__ float As[64][68];
    __shared__ float Ws[64][64];
    int tid = threadIdx.x;
    int tx = tid & 15, ty = tid >> 4;
    int rb = blockIdx.x * 64;
    float acc[4][4] = {};
    for (int kc = 0; kc < K; kc += 64) {
        __syncthreads();   // protect previous iteration's LDS reads
        for (int e = tid * 4; e < 64 * 64; e += 1024) {
            int r = e >> 6, k = e & 63;
            int gr = rb + r;
            float4 v = make_float4(0.f, 0.f, 0.f, 0.f);
            if (gr < M) v = *(const float4*)&A[(long)gr * K + kc + k];
            *(float4*)&As[r][k] = v;
        }
        for (int e = tid * 4; e < 64 * 64; e += 1024) {
            int r = e >> 6, k = e & 63;
            *(float4*)&Ws[r][k] = *(const float4*)&W[(long)(kc + r) * 64 + k];
        }
        __syncthreads();
#pragma unroll 16
        for (int k = 0; k < 64; ++k) {
            float a0 = As[ty * 4 + 0][k];
            float a1 = As[ty * 4 + 1][k];
            float a2 = As[ty * 4 + 2][k];
            float a3 = As[ty * 4 + 3][k];
            float4 b = *(float4*)&Ws[k][tx * 4];
            acc[0][0] = fmaf(a0, b.x, acc[0][0]); acc[0][1] = fmaf(a0, b.y, acc[0][1]);
            acc[0][2] = fmaf(a0, b.z, acc[0][2]); acc[0][3] = fmaf(a0, b.w, acc[0][3]);
            acc[1][0] = fmaf(a1, b.x, acc[1][0]); acc[1][1] = fmaf(a1, b.y, acc[1][1]);
            acc[1][2] = fmaf(a1, b.z, acc[1][2]); acc[1][3] = fmaf(a1, b.w, acc[1][3]);
            acc[2][0] = fmaf(a2, b.x, acc[2][0]); acc[2][1] = fmaf(a2, b.y, acc[2][1]);
            acc[2][2] = fmaf(a2, b.z, acc[2][2]); acc[2][3] = fmaf(a2, b.w, acc[2][3]);
            acc[3][0] = fmaf(a3, b.x, acc[3][0]); acc[3][1] = fmaf(a3, b.y, acc[3][1]);
            acc[3][2] = fmaf(a3, b.z, acc[3][2]); acc[3][3] = fmaf(a3, b.w, acc[3][3]);
        }
    }
#pragma unroll
    for (int j = 0; j < 4; ++j) {
        int gr = rb + ty * 4 + j;
        if (gr < M) {
            float4 v = make_float4(acc[j][0], acc[j][1], acc[j][2], acc[j][3]);
            *(float4*)&C[(long)gr * 64 + tx * 4] = v;
        }
    }
}

// ---------------------------------------------------------------- aggregation
// one wave per node, lane = feature. acc = h[i]*dinv[i]^2 (self loop) + bias,
// then gather-sum norm_e * h[src_e], 8-deep batched for memory-level
// parallelism (the serial-edge loop was latency-bound at 19% HBM).
// Tail batches use clamped indices + zero weights to keep 8 loads in flight.
__global__ __launch_bounds__(256) void k_agg(const float* __restrict__ h,
                                             const int* __restrict__ rp,
                                             const int* __restrict__ col,
                                             const float* __restrict__ val,
                                             const float* __restrict__ dinv,
                                             const float* __restrict__ bias,
                                             float* __restrict__ out, int N) {
    int wid  = (blockIdx.x * 256 + threadIdx.x) >> 6;
    int lane = threadIdx.x & 63;
    if (wid >= N) return;
    float di  = dinv[wid];
    float acc = fmaf(h[(long)wid * 64 + lane], di * di, bias[lane]);
    int e0 = rp[wid], e1 = rp[wid + 1];
    for (int base = e0; base < e1; base += 8) {
        int   s[8];
        float wv[8];
#pragma unroll
        for (int j = 0; j < 8; ++j) {
            int e   = base + j;
            int ok  = e < e1;
            int idx = ok ? e : e0;          // clamp: always a valid load
            s[j]  = col[idx];
            wv[j] = ok ? val[idx] : 0.0f;   // masked weight kills the duplicate
        }
        float hv[8];
#pragma unroll
        for (int j = 0; j < 8; ++j) hv[j] = h[(long)s[j] * 64 + lane];
#pragma unroll
        for (int j = 0; j < 8; ++j) acc = fmaf(wv[j], hv[j], acc);
    }
    out[(long)wid * 64 + lane] = fmaxf(acc, 0.0f);
}

// ---------------------------------------------------------------- FC: [M,64]@[64,10]+b
__global__ __launch_bounds__(256) void k_fc(const float* __restrict__ h,
                                            const float* __restrict__ W,
                                            const float* __restrict__ b,
                                            float* __restrict__ out, int N) {
    __shared__ float Ws[64 * 10];
    __shared__ float bs[16];
    int tid = threadIdx.x;
    for (int e = tid; e < 64 * 10; e += 256) Ws[e] = W[e];
    if (tid < 10) bs[tid] = b[tid];
    __syncthreads();
    int i = blockIdx.x * 256 + tid;
    if (i >= N) return;
    float acc[10];
#pragma unroll
    for (int j = 0; j < 10; ++j) acc[j] = bs[j];
    const float4* row = (const float4*)&h[(long)i * 64];
#pragma unroll
    for (int c = 0; c < 16; ++c) {
        float4 a = row[c];
#pragma unroll
        for (int j = 0; j < 10; ++j) {
            acc[j] = fmaf(a.x, Ws[(4 * c + 0) * 10 + j], acc[j]);
            acc[j] = fmaf(a.y, Ws[(4 * c + 1) * 10 + j], acc[j]);
            acc[j] = fmaf(a.z, Ws[(4 * c + 2) * 10 + j], acc[j]);
            acc[j] = fmaf(a.w, Ws[(4 * c + 3) * 10 + j], acc[j]);
        }
    }
#pragma unroll
    for (int j = 0; j < 10; ++j) out[(long)i * 10 + j] = acc[j];
}

// ---------------------------------------------------------------- launch
extern "C" void kernel_launch(void* const* d_in, const int* in_sizes, int n_in,
                              void* d_out, int out_size, void* d_ws, size_t ws_size,
                              hipStream_t stream) {
    const float* x    = (const float*)d_in[0];
    const void*  eidx = d_in[1];
    const float* ew   = (const float*)d_in[2];
    const float* W1   = (const float*)d_in[3];
    const float* b1   = (const float*)d_in[4];
    const float* W2   = (const float*)d_in[5];
    const float* b2   = (const float*)d_in[6];
    const float* Wfc  = (const float*)d_in[7];
    const float* bfc  = (const float*)d_in[8];
    float* out = (float*)d_out;

    const int N = in_sizes[0] / F_IN;   // 100000
    const int E = in_sizes[2];          // 1600000

    char* w = (char*)d_ws;
    size_t off = 0;
    auto alloc = [&](size_t bytes) {
        void* p = w + off;
        off += (bytes + 255) & ~(size_t)255;
        return p;
    };
    float* dinv = (float*)alloc((size_t)N * 4);        // deg, then rsqrt in-place
    int*   cnt  = (int*)alloc((size_t)N * 4);
    int*   rp   = (int*)alloc((size_t)(N + 1) * 4);
    int*   cur  = (int*)alloc((size_t)N * 4);
    int*   bsum = (int*)alloc(4096);
    int*   flag = (int*)alloc(256);
    int*   conv = (int*)alloc((size_t)2 * E * 4);      // src | dst as int32
    int*   col  = (int*)alloc((size_t)E * 4);
    float* val  = (float*)alloc((size_t)E * 4);
    float* h1   = (float*)alloc((size_t)N * F_H * 4);
    float* g    = (float*)alloc((size_t)N * F_H * 4);
    (void)ws_size;

    hipMemsetAsync(dinv, 0, (size_t)N * 4, stream);
    hipMemsetAsync(cnt,  0, (size_t)N * 4, stream);
    hipMemsetAsync(cur,  0, (size_t)N * 4, stream);

    const int NB = (N + 1023) / 1024;   // scan blocks (256 thr x 4 elem)

    k_detect<<<1, 64, 0, stream>>>((const unsigned long long*)eidx, flag);
    k_convert<<<(2 * E + 255) / 256, 256, 0, stream>>>(eidx, flag, conv, 2 * E);
    k_deg<<<(E + 255) / 256, 256, 0, stream>>>(conv + E, ew, dinv, cnt, E);
    k_dinv<<<(N + 255) / 256, 256, 0, stream>>>(dinv, N);
    k_scanA<<<NB, 256, 0, stream>>>(cnt, bsum, N);
    k_scanB<<<1, 64, 0, stream>>>(bsum, NB);
    k_scanC<<<NB, 256, 0, stream>>>(cnt, bsum, rp, N, E);
    k_scatter<<<(E + 255) / 256, 256, 0, stream>>>(conv, conv + E, ew, dinv, rp, cur,
                                                   col, val, E);

    const int GB = (N + 63) / 64;       // gemm row-tiles
    k_gemm<F_IN><<<GB, 256, 0, stream>>>(x, W1, h1, N);                 // h1 = x@W1
    k_agg<<<(N + 3) / 4, 256, 0, stream>>>(h1, rp, col, val, dinv, b1, g, N);
    k_gemm<F_H><<<GB, 256, 0, stream>>>(g, W2, h1, N);                  // h2pre = g@W2
    k_agg<<<(N + 3) / 4, 256, 0, stream>>>(h1, rp, col, val, dinv, b2, g, N);
    k_fc<<<(N + 255) / 256, 256, 0, stream>>>(g, Wfc, bfc, out, N);
}

// Round 3
// 336.935 us; speedup vs baseline: 1.8869x; 1.3448x over previous
//
#include <hip/hip_runtime.h>

static constexpr int F_IN  = 128;
static constexpr int F_H   = 64;
static constexpr int F_OUT = 10;

static constexpr int NPB_SHIFT = 7;          // nodes per bucket = 128
static constexpr int NPB   = 1 << NPB_SHIFT;
static constexpr int MAXB  = 1024;           // max buckets (N <= 131072)
static constexpr int EPB   = 8192;           // edges per partition block

// ---------------------------------------------------------------- detect
// edge_index may arrive as int64 (reference dtype) or int32 (JAX default
// demotion). If the high 32 bits of the first 64 u64 words are all zero,
// it's int64 (values < 100000).
__global__ __launch_bounds__(64) void k_detect(const unsigned long long* __restrict__ u,
                                               int* __restrict__ flag) {
    unsigned long long v = u[threadIdx.x];
    int hz = ((v >> 32) == 0ull) ? 1 : 0;
    int all64 = __all(hz);
    if (threadIdx.x == 0) flag[0] = all64;
}

__device__ __forceinline__ int load_idx(const void* ein, bool f64, long i) {
    return f64 ? (int)((const long long*)ein)[i] : ((const int*)ein)[i];
}

// ---------------------------------------------------------------- coarse histogram
// LDS histogram of dst>>NPB_SHIFT; one global atomicAdd per nonzero bin per block.
__global__ __launch_bounds__(256) void k_coarse(const void* __restrict__ ein,
                                                const int* __restrict__ flag,
                                                int* __restrict__ gcnt, int E, int B) {
    __shared__ int l[MAXB];
    int tid = threadIdx.x;
    for (int i = tid; i < B; i += 256) l[i] = 0;
    __syncthreads();
    bool f = flag[0];
    int base = blockIdx.x * EPB;
#pragma unroll 4
    for (int j = 0; j < EPB / 256; ++j) {
        int e = base + j * 256 + tid;
        if (e < E) {
            int d = load_idx(ein, f, (long)E + e);
            atomicAdd(&l[d >> NPB_SHIFT], 1);
        }
    }
    __syncthreads();
    for (int i = tid; i < B; i += 256)
        if (l[i]) atomicAdd(&gcnt[i], l[i]);
}

// ---------------------------------------------------------------- coarse scan (1 block)
__global__ __launch_bounds__(256) void k_scan_coarse(const int* __restrict__ gcnt,
                                                     int* __restrict__ gbase, int B, int E) {
    __shared__ int sm[256];
    int tid = threadIdx.x;
    int c[4]; int s = 0;
#pragma unroll
    for (int j = 0; j < 4; ++j) {
        int i = tid * 4 + j;
        c[j] = (i < B) ? gcnt[i] : 0;
        s += c[j];
    }
    sm[tid] = s;
    __syncthreads();
    for (int off = 1; off < 256; off <<= 1) {
        int v = 0;
        if (tid >= off) v = sm[tid - off];
        __syncthreads();
        sm[tid] += v;
        __syncthreads();
    }
    int run = sm[tid] - s;
#pragma unroll
    for (int j = 0; j < 4; ++j) {
        int i = tid * 4 + j;
        if (i < B) gbase[i] = run;
        run += c[j];
    }
    if (tid == 0) gbase[B] = E;
}

// ---------------------------------------------------------------- partition
// Bucket edges by dst. Per-block: LDS count -> one global reservation atomic
// per bucket -> LDS-cursor scatter. No per-edge global atomics.
__global__ __launch_bounds__(256) void k_partition(const void* __restrict__ ein,
                                                   const float* __restrict__ ew,
                                                   const int* __restrict__ flag,
                                                   const int* __restrict__ gbase,
                                                   int* __restrict__ gcur,
                                                   int* __restrict__ bsrc,
                                                   int* __restrict__ bdst,
                                                   float* __restrict__ bew,
                                                   int E, int B) {
    __shared__ int lcnt[MAXB];
    __shared__ int lofs[MAXB];
    int tid = threadIdx.x;
    for (int i = tid; i < B; i += 256) lcnt[i] = 0;
    __syncthreads();
    bool f = flag[0];
    int base = blockIdx.x * EPB;
#pragma unroll 4
    for (int j = 0; j < EPB / 256; ++j) {
        int e = base + j * 256 + tid;
        if (e < E) {
            int d = load_idx(ein, f, (long)E + e);
            atomicAdd(&lcnt[d >> NPB_SHIFT], 1);
        }
    }
    __syncthreads();
    for (int i = tid; i < B; i += 256) {
        int c = lcnt[i];
        lofs[i] = c ? atomicAdd(&gcur[i], c) : 0;
        lcnt[i] = 0;   // reuse as local cursor
    }
    __syncthreads();
#pragma unroll 4
    for (int j = 0; j < EPB / 256; ++j) {
        int e = base + j * 256 + tid;
        if (e < E) {
            int s = load_idx(ein, f, e);
            int d = load_idx(ein, f, (long)E + e);
            float w = ew[e];
            int b = d >> NPB_SHIFT;
            int p = gbase[b] + lofs[b] + atomicAdd(&lcnt[b], 1);
            bsrc[p] = s;
            bdst[p] = d;
            bew[p]  = w;
        }
    }
}

// ---------------------------------------------------------------- per-bucket hist
// One block per bucket: LDS cnt/deg histogram (LDS atomics), then direct
// global writes of cnt and dinv = rsqrt(deg + 1). Zero global atomics.
__global__ __launch_bounds__(256) void k_bucket_hist(const int* __restrict__ bdst,
                                                     const float* __restrict__ bew,
                                                     const int* __restrict__ gbase,
                                                     int* __restrict__ cnt,
                                                     float* __restrict__ dinv, int N) {
    __shared__ int   lc[NPB];
    __shared__ float ld[NPB];
    int b = blockIdx.x, tid = threadIdx.x;
    for (int i = tid; i < NPB; i += 256) { lc[i] = 0; ld[i] = 0.0f; }
    __syncthreads();
    int p0 = gbase[b], p1 = gbase[b + 1];
    for (int p = p0 + tid; p < p1; p += 256) {
        int d = bdst[p] & (NPB - 1);
        atomicAdd(&lc[d], 1);
        atomicAdd(&ld[d], bew[p]);
    }
    __syncthreads();
    int nb = b << NPB_SHIFT;
    for (int i = tid; i < NPB; i += 256) {
        int node = nb + i;
        if (node < N) {
            cnt[node]  = lc[i];
            dinv[node] = rsqrtf(ld[i] + 1.0f);   // + self-loop weight 1
        }
    }
}

// ---------------------------------------------------------------- 3-pass scan (row_ptr)
__global__ __launch_bounds__(256) void k_scanA(const int* __restrict__ cnt,
                                               int* __restrict__ bsum, int N) {
    int gid = blockIdx.x * 256 + threadIdx.x;
    int s = 0;
#pragma unroll
    for (int j = 0; j < 4; ++j) {
        int i = gid * 4 + j;
        if (i < N) s += cnt[i];
    }
    __shared__ int sm[256];
    sm[threadIdx.x] = s;
    __syncthreads();
    for (int off = 128; off > 0; off >>= 1) {
        if (threadIdx.x < off) sm[threadIdx.x] += sm[threadIdx.x + off];
        __syncthreads();
    }
    if (threadIdx.x == 0) bsum[blockIdx.x] = sm[0];
}

__global__ void k_scanB(int* __restrict__ bsum, int nb) {
    if (threadIdx.x == 0 && blockIdx.x == 0) {
        int acc = 0;
        for (int i = 0; i < nb; ++i) { int v = bsum[i]; bsum[i] = acc; acc += v; }
    }
}

__global__ __launch_bounds__(256) void k_scanC(const int* __restrict__ cnt,
                                               const int* __restrict__ bsum,
                                               int* __restrict__ rp, int N, int E) {
    int tid = threadIdx.x;
    int gid = blockIdx.x * 256 + tid;
    int c[4]; int s = 0;
#pragma unroll
    for (int j = 0; j < 4; ++j) {
        int i = gid * 4 + j;
        c[j] = (i < N) ? cnt[i] : 0;
        s += c[j];
    }
    __shared__ int sm[256];
    sm[tid] = s;
    __syncthreads();
    for (int off = 1; off < 256; off <<= 1) {
        int v = 0;
        if (tid >= off) v = sm[tid - off];
        __syncthreads();
        sm[tid] += v;
        __syncthreads();
    }
    int run = bsum[blockIdx.x] + (sm[tid] - s);
#pragma unroll
    for (int j = 0; j < 4; ++j) {
        int i = gid * 4 + j;
        if (i < N) rp[i] = run;
        run += c[j];
    }
    if (gid == 0) rp[N] = E;
}

// ---------------------------------------------------------------- per-bucket CSR scatter
// One block per bucket: LDS per-node cursors. col/val writes land in the
// bucket's contiguous rp-span. Zero global atomics.
__global__ __launch_bounds__(256) void k_bucket_scatter(const int* __restrict__ bsrc,
                                                        const int* __restrict__ bdst,
                                                        const float* __restrict__ bew,
                                                        const int* __restrict__ gbase,
                                                        const int* __restrict__ rp,
                                                        const float* __restrict__ dinv,
                                                        int* __restrict__ col,
                                                        float* __restrict__ val) {
    __shared__ int lcur[NPB];
    int b = blockIdx.x, tid = threadIdx.x;
    for (int i = tid; i < NPB; i += 256) lcur[i] = 0;
    __syncthreads();
    int p0 = gbase[b], p1 = gbase[b + 1];
    for (int p = p0 + tid; p < p1; p += 256) {
        int d = bdst[p], s = bsrc[p];
        float nv = dinv[s] * bew[p] * dinv[d];
        int pos = rp[d] + atomicAdd(&lcur[d & (NPB - 1)], 1);
        col[pos] = s;
        val[pos] = nv;
    }
}

// ---------------------------------------------------------------- GEMM: [M,K]@[K,64]
template <int K>
__global__ __launch_bounds__(256) void k_gemm(const float* __restrict__ A,
                                              const float* __restrict__ W,
                                              float* __restrict__ C, int M) {
    __shared__ float As[64][68];
    __shared__ float Ws[64][64];
    int tid = threadIdx.x;
    int tx = tid & 15, ty = tid >> 4;
    int rb = blockIdx.x * 64;
    float acc[4][4] = {};
    for (int kc = 0; kc < K; kc += 64) {
        __syncthreads();
        for (int e = tid * 4; e < 64 * 64; e += 1024) {
            int r = e >> 6, k = e & 63;
            int gr = rb + r;
            float4 v = make_float4(0.f, 0.f, 0.f, 0.f);
            if (gr < M) v = *(const float4*)&A[(long)gr * K + kc + k];
            *(float4*)&As[r][k] = v;
        }
        for (int e = tid * 4; e < 64 * 64; e += 1024) {
            int r = e >> 6, k = e & 63;
            *(float4*)&Ws[r][k] = *(const float4*)&W[(long)(kc + r) * 64 + k];
        }
        __syncthreads();
#pragma unroll 16
        for (int k = 0; k < 64; ++k) {
            float a0 = As[ty * 4 + 0][k];
            float a1 = As[ty * 4 + 1][k];
            float a2 = As[ty * 4 + 2][k];
            float a3 = As[ty * 4 + 3][k];
            float4 b = *(float4*)&Ws[k][tx * 4];
            acc[0][0] = fmaf(a0, b.x, acc[0][0]); acc[0][1] = fmaf(a0, b.y, acc[0][1]);
            acc[0][2] = fmaf(a0, b.z, acc[0][2]); acc[0][3] = fmaf(a0, b.w, acc[0][3]);
            acc[1][0] = fmaf(a1, b.x, acc[1][0]); acc[1][1] = fmaf(a1, b.y, acc[1][1]);
            acc[1][2] = fmaf(a1, b.z, acc[1][2]); acc[1][3] = fmaf(a1, b.w, acc[1][3]);
            acc[2][0] = fmaf(a2, b.x, acc[2][0]); acc[2][1] = fmaf(a2, b.y, acc[2][1]);
            acc[2][2] = fmaf(a2, b.z, acc[2][2]); acc[2][3] = fmaf(a2, b.w, acc[2][3]);
            acc[3][0] = fmaf(a3, b.x, acc[3][0]); acc[3][1] = fmaf(a3, b.y, acc[3][1]);
            acc[3][2] = fmaf(a3, b.z, acc[3][2]); acc[3][3] = fmaf(a3, b.w, acc[3][3]);
        }
    }
#pragma unroll
    for (int j = 0; j < 4; ++j) {
        int gr = rb + ty * 4 + j;
        if (gr < M) {
            float4 v = make_float4(acc[j][0], acc[j][1], acc[j][2], acc[j][3]);
            *(float4*)&C[(long)gr * 64 + tx * 4] = v;
        }
    }
}

// ---------------------------------------------------------------- aggregation
// one wave per node, lane = feature; 8-deep batched gathers for MLP.
__global__ __launch_bounds__(256) void k_agg(const float* __restrict__ h,
                                             const int* __restrict__ rp,
                                             const int* __restrict__ col,
                                             const float* __restrict__ val,
                                             const float* __restrict__ dinv,
                                             const float* __restrict__ bias,
                                             float* __restrict__ out, int N) {
    int wid  = (blockIdx.x * 256 + threadIdx.x) >> 6;
    int lane = threadIdx.x & 63;
    if (wid >= N) return;
    float di  = dinv[wid];
    float acc = fmaf(h[(long)wid * 64 + lane], di * di, bias[lane]);
    int e0 = rp[wid], e1 = rp[wid + 1];
    for (int base = e0; base < e1; base += 8) {
        int   s[8];
        float wv[8];
#pragma unroll
        for (int j = 0; j < 8; ++j) {
            int e   = base + j;
            int ok  = e < e1;
            int idx = ok ? e : e0;
            s[j]  = col[idx];
            wv[j] = ok ? val[idx] : 0.0f;
        }
        float hv[8];
#pragma unroll
        for (int j = 0; j < 8; ++j) hv[j] = h[(long)s[j] * 64 + lane];
#pragma unroll
        for (int j = 0; j < 8; ++j) acc = fmaf(wv[j], hv[j], acc);
    }
    out[(long)wid * 64 + lane] = fmaxf(acc, 0.0f);
}

// ---------------------------------------------------------------- FC: [M,64]@[64,10]+b
__global__ __launch_bounds__(256) void k_fc(const float* __restrict__ h,
                                            const float* __restrict__ W,
                                            const float* __restrict__ b,
                                            float* __restrict__ out, int N) {
    __shared__ float Ws[64 * 10];
    __shared__ float bs[16];
    int tid = threadIdx.x;
    for (int e = tid; e < 64 * 10; e += 256) Ws[e] = W[e];
    if (tid < 10) bs[tid] = b[tid];
    __syncthreads();
    int i = blockIdx.x * 256 + tid;
    if (i >= N) return;
    float acc[10];
#pragma unroll
    for (int j = 0; j < 10; ++j) acc[j] = bs[j];
    const float4* row = (const float4*)&h[(long)i * 64];
#pragma unroll
    for (int c = 0; c < 16; ++c) {
        float4 a = row[c];
#pragma unroll
        for (int j = 0; j < 10; ++j) {
            acc[j] = fmaf(a.x, Ws[(4 * c + 0) * 10 + j], acc[j]);
            acc[j] = fmaf(a.y, Ws[(4 * c + 1) * 10 + j], acc[j]);
            acc[j] = fmaf(a.z, Ws[(4 * c + 2) * 10 + j], acc[j]);
            acc[j] = fmaf(a.w, Ws[(4 * c + 3) * 10 + j], acc[j]);
        }
    }
#pragma unroll
    for (int j = 0; j < 10; ++j) out[(long)i * 10 + j] = acc[j];
}

// ---------------------------------------------------------------- launch
extern "C" void kernel_launch(void* const* d_in, const int* in_sizes, int n_in,
                              void* d_out, int out_size, void* d_ws, size_t ws_size,
                              hipStream_t stream) {
    const float* x    = (const float*)d_in[0];
    const void*  eidx = d_in[1];
    const float* ew   = (const float*)d_in[2];
    const float* W1   = (const float*)d_in[3];
    const float* b1   = (const float*)d_in[4];
    const float* W2   = (const float*)d_in[5];
    const float* b2   = (const float*)d_in[6];
    const float* Wfc  = (const float*)d_in[7];
    const float* bfc  = (const float*)d_in[8];
    float* out = (float*)d_out;

    const int N = in_sizes[0] / F_IN;   // 100000
    const int E = in_sizes[2];          // 1600000
    const int B = (N + NPB - 1) >> NPB_SHIFT;   // 782 buckets

    char* w = (char*)d_ws;
    size_t off = 0;
    auto alloc = [&](size_t bytes) {
        void* p = w + off;
        off += (bytes + 255) & ~(size_t)255;
        return p;
    };
    float* dinv  = (float*)alloc((size_t)N * 4);
    int*   cnt   = (int*)alloc((size_t)N * 4);
    int*   rp    = (int*)alloc((size_t)(N + 1) * 4);
    int*   bsum  = (int*)alloc(4096);
    int*   flag  = (int*)alloc(256);
    int*   gcnt  = (int*)alloc((size_t)MAXB * 4);
    int*   gbase = (int*)alloc((size_t)(MAXB + 1) * 4);
    int*   gcur  = (int*)alloc((size_t)MAXB * 4);
    int*   bsrc  = (int*)alloc((size_t)E * 4);
    int*   bdst  = (int*)alloc((size_t)E * 4);
    float* bew   = (float*)alloc((size_t)E * 4);
    int*   col   = (int*)alloc((size_t)E * 4);
    float* val   = (float*)alloc((size_t)E * 4);
    float* h1    = (float*)alloc((size_t)N * F_H * 4);
    float* g     = (float*)alloc((size_t)N * F_H * 4);
    (void)ws_size;

    hipMemsetAsync(gcnt, 0, (size_t)B * 4, stream);
    hipMemsetAsync(gcur, 0, (size_t)B * 4, stream);

    const int PB = (E + EPB - 1) / EPB;   // partition blocks
    const int NB = (N + 1023) / 1024;     // node-scan blocks

    k_detect<<<1, 64, 0, stream>>>((const unsigned long long*)eidx, flag);
    k_coarse<<<PB, 256, 0, stream>>>(eidx, flag, gcnt, E, B);
    k_scan_coarse<<<1, 256, 0, stream>>>(gcnt, gbase, B, E);
    k_partition<<<PB, 256, 0, stream>>>(eidx, ew, flag, gbase, gcur, bsrc, bdst, bew, E, B);
    k_bucket_hist<<<B, 256, 0, stream>>>(bdst, bew, gbase, cnt, dinv, N);
    k_scanA<<<NB, 256, 0, stream>>>(cnt, bsum, N);
    k_scanB<<<1, 64, 0, stream>>>(bsum, NB);
    k_scanC<<<NB, 256, 0, stream>>>(cnt, bsum, rp, N, E);
    k_bucket_scatter<<<B, 256, 0, stream>>>(bsrc, bdst, bew, gbase, rp, dinv, col, val);

    const int GB = (N + 63) / 64;
    k_gemm<F_IN><<<GB, 256, 0, stream>>>(x, W1, h1, N);                 // h1 = x@W1
    k_agg<<<(N + 3) / 4, 256, 0, stream>>>(h1, rp, col, val, dinv, b1, g, N);
    k_gemm<F_H><<<GB, 256, 0, stream>>>(g, W2, h1, N);                  // h2pre = g@W2
    k_agg<<<(N + 3) / 4, 256, 0, stream>>>(h1, rp, col, val, dinv, b2, g, N);
    k_fc<<<(N + 255) / 256, 256, 0, stream>>>(g, Wfc, bfc, out, N);
}

// Round 4
// 280.992 us; speedup vs baseline: 2.2626x; 1.1991x over previous
//
#include <hip/hip_runtime.h>

static constexpr int F_IN  = 128;
static constexpr int F_H   = 64;
static constexpr int F_OUT = 10;

static constexpr int NPB_SHIFT = 9;            // 512 nodes per coarse bucket
static constexpr int NPB = 1 << NPB_SHIFT;
static constexpr int MAXC = 256;               // max coarse buckets (N <= 131072)
static constexpr int EPB = 2048;               // edges per part1 block

// ---------------------------------------------------------------- detect
// edge_index may arrive as int64 (reference dtype) or int32 (JAX default
// demotion). If the high 32 bits of the first 64 u64 words are all zero,
// it's int64 (values < 100000).
__global__ __launch_bounds__(64) void k_detect(const unsigned long long* __restrict__ u,
                                               int* __restrict__ flag) {
    unsigned long long v = u[threadIdx.x];
    int hz = ((v >> 32) == 0ull) ? 1 : 0;
    int all64 = __all(hz);
    if (threadIdx.x == 0) flag[0] = all64;
}

__device__ __forceinline__ int load_idx(const void* ein, bool f64, long i) {
    return f64 ? (int)((const long long*)ein)[i] : ((const int*)ein)[i];
}

// ---------------------------------------------------------------- level-1 partition
// Bucket edges by dst>>9 into fixed-capacity spans of the packed array.
// Packed u64: [0:32) = w bits, [32:49) = src, [49:58) = dst & 511.
// Per block: LDS hist -> one reservation atomic per nonzero bin -> scatter.
__global__ __launch_bounds__(256) void k_part1(const void* __restrict__ ein,
                                               const float* __restrict__ ew,
                                               const int* __restrict__ flag,
                                               int* __restrict__ gcur,
                                               unsigned long long* __restrict__ packed,
                                               int E, int NC, int cap) {
    __shared__ int lcnt[MAXC];
    __shared__ int lofs[MAXC];
    int tid = threadIdx.x;
    if (tid < NC) lcnt[tid] = 0;
    __syncthreads();
    bool f = flag[0];
    int base = blockIdx.x * EPB;
#pragma unroll
    for (int j = 0; j < EPB / 256; ++j) {
        int e = base + j * 256 + tid;
        if (e < E) {
            int d = load_idx(ein, f, (long)E + e);
            atomicAdd(&lcnt[d >> NPB_SHIFT], 1);
        }
    }
    __syncthreads();
    if (tid < NC) {
        int c = lcnt[tid];
        lofs[tid] = c ? atomicAdd(&gcur[tid], c) : 0;
        lcnt[tid] = 0;   // reuse as local cursor
    }
    __syncthreads();
#pragma unroll
    for (int j = 0; j < EPB / 256; ++j) {
        int e = base + j * 256 + tid;
        if (e < E) {
            int s = load_idx(ein, f, e);
            int d = load_idx(ein, f, (long)E + e);
            unsigned int wb = __float_as_uint(ew[e]);
            int b = d >> NPB_SHIFT;
            int pos = lofs[b] + atomicAdd(&lcnt[b], 1);
            if (pos < cap) {
                unsigned long long u = (unsigned long long)wb
                                     | ((unsigned long long)(unsigned)s << 32)
                                     | ((unsigned long long)(unsigned)(d & (NPB - 1)) << 49);
                packed[(long)b * cap + pos] = u;
            }
        }
    }
}

// ---------------------------------------------------------------- bucket-count scan
// One block: exclusive scan of gcur[NC] -> gbase (edge base per bucket);
// also gbase[NC] = E and rp[N] = E.
__global__ __launch_bounds__(256) void k_scanNC(const int* __restrict__ gcur,
                                                int* __restrict__ gbase,
                                                int* __restrict__ rp,
                                                int NC, int N, int E) {
    __shared__ int sm[256];
    int tid = threadIdx.x;
    int c = (tid < NC) ? gcur[tid] : 0;
    sm[tid] = c;
    __syncthreads();
    for (int off = 1; off < 256; off <<= 1) {
        int v = 0;
        if (tid >= off) v = sm[tid - off];
        __syncthreads();
        sm[tid] += v;
        __syncthreads();
    }
    if (tid < NC) gbase[tid] = sm[tid] - c;
    if (tid == 0) { gbase[NC] = E; rp[N] = E; }
}

// ---------------------------------------------------------------- per-bucket hist + scan
// One block per bucket: LDS cnt/deg over 512 local nodes (LDS atomics),
// in-block scan -> writes rp[node] = gbase[b] + local_excl and
// dinv[node] = rsqrt(deg + 1). Zero global atomics.
__global__ __launch_bounds__(256) void k_chist(const unsigned long long* __restrict__ packed,
                                               const int* __restrict__ gcur,
                                               const int* __restrict__ gbase,
                                               int* __restrict__ rp,
                                               float* __restrict__ dinv,
                                               int N, int cap) {
    __shared__ int   lc[NPB];
    __shared__ float ld[NPB];
    __shared__ int   sm[256];
    int b = blockIdx.x, tid = threadIdx.x;
#pragma unroll
    for (int i = tid; i < NPB; i += 256) { lc[i] = 0; ld[i] = 0.0f; }
    __syncthreads();
    int cnt = gcur[b];
    const unsigned long long* pk = packed + (long)b * cap;
    for (int p = tid; p < cnt; p += 256) {
        unsigned long long u = pk[p];
        int dl = (int)(u >> 49);
        atomicAdd(&lc[dl], 1);
        atomicAdd(&ld[dl], __uint_as_float((unsigned int)u));
    }
    __syncthreads();
    // scan 512 entries with 256 threads, 2 consecutive slots each
    int c0 = lc[tid * 2], c1 = lc[tid * 2 + 1];
    int s = c0 + c1;
    sm[tid] = s;
    __syncthreads();
    for (int off = 1; off < 256; off <<= 1) {
        int v = 0;
        if (tid >= off) v = sm[tid - off];
        __syncthreads();
        sm[tid] += v;
        __syncthreads();
    }
    int excl = sm[tid] - s + gbase[b];
    int n0 = b << NPB_SHIFT;
    int node0 = n0 + tid * 2, node1 = node0 + 1;
    if (node0 < N) {
        rp[node0]   = excl;
        dinv[node0] = rsqrtf(ld[tid * 2] + 1.0f);
    }
    if (node1 < N) {
        rp[node1]   = excl + c0;
        dinv[node1] = rsqrtf(ld[tid * 2 + 1] + 1.0f);
    }
}

// ---------------------------------------------------------------- per-bucket CSR scatter
// One block per bucket: LDS absolute cursors (= rp[node]); emits col/val.
// Write span per block ~ bucket edge range -> L2 resident, lines fully written.
__global__ __launch_bounds__(256) void k_cscatter(const unsigned long long* __restrict__ packed,
                                                  const int* __restrict__ gcur,
                                                  const int* __restrict__ rp,
                                                  const float* __restrict__ dinv,
                                                  int* __restrict__ col,
                                                  float* __restrict__ val,
                                                  int N, int cap) {
    __shared__ int   cur[NPB];
    __shared__ float dd[NPB];
    int b = blockIdx.x, tid = threadIdx.x;
    int n0 = b << NPB_SHIFT;
#pragma unroll
    for (int i = tid; i < NPB; i += 256) {
        int node = n0 + i;
        cur[i] = (node < N) ? rp[node]   : 0;
        dd[i]  = (node < N) ? dinv[node] : 0.0f;
    }
    __syncthreads();
    int cnt = gcur[b];
    const unsigned long long* pk = packed + (long)b * cap;
    for (int p = tid; p < cnt; p += 256) {
        unsigned long long u = pk[p];
        int dl = (int)(u >> 49);
        int s  = (int)((u >> 32) & 0x1FFFF);
        float w = __uint_as_float((unsigned int)u);
        int pos = atomicAdd(&cur[dl], 1);
        col[pos] = s;
        val[pos] = dinv[s] * w * dd[dl];
    }
}

// ---------------------------------------------------------------- GEMM: [M,K]@[K,64]
template <int K>
__global__ __launch_bounds__(256) void k_gemm(const float* __restrict__ A,
                                              const float* __restrict__ W,
                                              float* __restrict__ C, int M) {
    __shared__ float As[64][68];
    __shared__ float Ws[64][64];
    int tid = threadIdx.x;
    int tx = tid & 15, ty = tid >> 4;
    int rb = blockIdx.x * 64;
    float acc[4][4] = {};
    for (int kc = 0; kc < K; kc += 64) {
        __syncthreads();
        for (int e = tid * 4; e < 64 * 64; e += 1024) {
            int r = e >> 6, k = e & 63;
            int gr = rb + r;
            float4 v = make_float4(0.f, 0.f, 0.f, 0.f);
            if (gr < M) v = *(const float4*)&A[(long)gr * K + kc + k];
            *(float4*)&As[r][k] = v;
        }
        for (int e = tid * 4; e < 64 * 64; e += 1024) {
            int r = e >> 6, k = e & 63;
            *(float4*)&Ws[r][k] = *(const float4*)&W[(long)(kc + r) * 64 + k];
        }
        __syncthreads();
#pragma unroll 16
        for (int k = 0; k < 64; ++k) {
            float a0 = As[ty * 4 + 0][k];
            float a1 = As[ty * 4 + 1][k];
            float a2 = As[ty * 4 + 2][k];
            float a3 = As[ty * 4 + 3][k];
            float4 b = *(float4*)&Ws[k][tx * 4];
            acc[0][0] = fmaf(a0, b.x, acc[0][0]); acc[0][1] = fmaf(a0, b.y, acc[0][1]);
            acc[0][2] = fmaf(a0, b.z, acc[0][2]); acc[0][3] = fmaf(a0, b.w, acc[0][3]);
            acc[1][0] = fmaf(a1, b.x, acc[1][0]); acc[1][1] = fmaf(a1, b.y, acc[1][1]);
            acc[1][2] = fmaf(a1, b.z, acc[1][2]); acc[1][3] = fmaf(a1, b.w, acc[1][3]);
            acc[2][0] = fmaf(a2, b.x, acc[2][0]); acc[2][1] = fmaf(a2, b.y, acc[2][1]);
            acc[2][2] = fmaf(a2, b.z, acc[2][2]); acc[2][3] = fmaf(a2, b.w, acc[2][3]);
            acc[3][0] = fmaf(a3, b.x, acc[3][0]); acc[3][1] = fmaf(a3, b.y, acc[3][1]);
            acc[3][2] = fmaf(a3, b.z, acc[3][2]); acc[3][3] = fmaf(a3, b.w, acc[3][3]);
        }
    }
#pragma unroll
    for (int j = 0; j < 4; ++j) {
        int gr = rb + ty * 4 + j;
        if (gr < M) {
            float4 v = make_float4(acc[j][0], acc[j][1], acc[j][2], acc[j][3]);
            *(float4*)&C[(long)gr * 64 + tx * 4] = v;
        }
    }
}

// ---------------------------------------------------------------- aggregation
// one wave per node, lane = feature; 8-deep batched gathers for MLP.
__global__ __launch_bounds__(256) void k_agg(const float* __restrict__ h,
                                             const int* __restrict__ rp,
                                             const int* __restrict__ col,
                                             const float* __restrict__ val,
                                             const float* __restrict__ dinv,
                                             const float* __restrict__ bias,
                                             float* __restrict__ out, int N) {
    int wid  = (blockIdx.x * 256 + threadIdx.x) >> 6;
    int lane = threadIdx.x & 63;
    if (wid >= N) return;
    float di  = dinv[wid];
    float acc = fmaf(h[(long)wid * 64 + lane], di * di, bias[lane]);
    int e0 = rp[wid], e1 = rp[wid + 1];
    for (int base = e0; base < e1; base += 8) {
        int   s[8];
        float wv[8];
#pragma unroll
        for (int j = 0; j < 8; ++j) {
            int e   = base + j;
            int ok  = e < e1;
            int idx = ok ? e : e0;
            s[j]  = col[idx];
            wv[j] = ok ? val[idx] : 0.0f;
        }
        float hv[8];
#pragma unroll
        for (int j = 0; j < 8; ++j) hv[j] = h[(long)s[j] * 64 + lane];
#pragma unroll
        for (int j = 0; j < 8; ++j) acc = fmaf(wv[j], hv[j], acc);
    }
    out[(long)wid * 64 + lane] = fmaxf(acc, 0.0f);
}

// ---------------------------------------------------------------- FC: [M,64]@[64,10]+b
__global__ __launch_bounds__(256) void k_fc(const float* __restrict__ h,
                                            const float* __restrict__ W,
                                            const float* __restrict__ b,
                                            float* __restrict__ out, int N) {
    __shared__ float Ws[64 * 10];
    __shared__ float bs[16];
    int tid = threadIdx.x;
    for (int e = tid; e < 64 * 10; e += 256) Ws[e] = W[e];
    if (tid < 10) bs[tid] = b[tid];
    __syncthreads();
    int i = blockIdx.x * 256 + tid;
    if (i >= N) return;
    float acc[10];
#pragma unroll
    for (int j = 0; j < 10; ++j) acc[j] = bs[j];
    const float4* row = (const float4*)&h[(long)i * 64];
#pragma unroll
    for (int c = 0; c < 16; ++c) {
        float4 a = row[c];
#pragma unroll
        for (int j = 0; j < 10; ++j) {
            acc[j] = fmaf(a.x, Ws[(4 * c + 0) * 10 + j], acc[j]);
            acc[j] = fmaf(a.y, Ws[(4 * c + 1) * 10 + j], acc[j]);
            acc[j] = fmaf(a.z, Ws[(4 * c + 2) * 10 + j], acc[j]);
            acc[j] = fmaf(a.w, Ws[(4 * c + 3) * 10 + j], acc[j]);
        }
    }
#pragma unroll
    for (int j = 0; j < 10; ++j) out[(long)i * 10 + j] = acc[j];
}

// ---------------------------------------------------------------- launch
extern "C" void kernel_launch(void* const* d_in, const int* in_sizes, int n_in,
                              void* d_out, int out_size, void* d_ws, size_t ws_size,
                              hipStream_t stream) {
    const float* x    = (const float*)d_in[0];
    const void*  eidx = d_in[1];
    const float* ew   = (const float*)d_in[2];
    const float* W1   = (const float*)d_in[3];
    const float* b1   = (const float*)d_in[4];
    const float* W2   = (const float*)d_in[5];
    const float* b2   = (const float*)d_in[6];
    const float* Wfc  = (const float*)d_in[7];
    const float* bfc  = (const float*)d_in[8];
    float* out = (float*)d_out;

    const int N  = in_sizes[0] / F_IN;            // 100000
    const int E  = in_sizes[2];                   // 1600000
    const int NC = (N + NPB - 1) >> NPB_SHIFT;    // 196 coarse buckets
    const int cap = E / NC + E / (2 * NC) + 1024; // ~1.6x mean + slack

    char* w = (char*)d_ws;
    size_t off = 0;
    auto alloc = [&](size_t bytes) {
        void* p = w + off;
        off += (bytes + 255) & ~(size_t)255;
        return p;
    };
    float* dinv  = (float*)alloc((size_t)N * 4);
    int*   rp    = (int*)alloc((size_t)(N + 1) * 4);
    int*   flag  = (int*)alloc(256);
    int*   gcur  = (int*)alloc((size_t)MAXC * 4);
    int*   gbase = (int*)alloc((size_t)(MAXC + 1) * 4);
    unsigned long long* packed =
        (unsigned long long*)alloc((size_t)NC * cap * 8);
    int*   col   = (int*)alloc((size_t)E * 4);
    float* val   = (float*)alloc((size_t)E * 4);
    float* h1    = (float*)alloc((size_t)N * F_H * 4);
    float* g     = (float*)alloc((size_t)N * F_H * 4);
    (void)ws_size;

    hipMemsetAsync(gcur, 0, (size_t)NC * 4, stream);

    const int PB = (E + EPB - 1) / EPB;   // 782 part1 blocks

    k_detect<<<1, 64, 0, stream>>>((const unsigned long long*)eidx, flag);
    k_part1<<<PB, 256, 0, stream>>>(eidx, ew, flag, gcur, packed, E, NC, cap);
    k_scanNC<<<1, 256, 0, stream>>>(gcur, gbase, rp, NC, N, E);
    k_chist<<<NC, 256, 0, stream>>>(packed, gcur, gbase, rp, dinv, N, cap);
    k_cscatter<<<NC, 256, 0, stream>>>(packed, gcur, rp, dinv, col, val, N, cap);

    const int GB = (N + 63) / 64;
    k_gemm<F_IN><<<GB, 256, 0, stream>>>(x, W1, h1, N);                 // h1 = x@W1
    k_agg<<<(N + 3) / 4, 256, 0, stream>>>(h1, rp, col, val, dinv, b1, g, N);
    k_gemm<F_H><<<GB, 256, 0, stream>>>(g, W2, h1, N);                  // h2pre = g@W2
    k_agg<<<(N + 3) / 4, 256, 0, stream>>>(h1, rp, col, val, dinv, b2, g, N);
    k_fc<<<(N + 255) / 256, 256, 0, stream>>>(g, Wfc, bfc, out, N);
}

// Round 5
// 270.018 us; speedup vs baseline: 2.3545x; 1.0406x over previous
//
#include <hip/hip_runtime.h>

static constexpr int F_IN  = 128;
static constexpr int F_H   = 64;
static constexpr int F_OUT = 10;

static constexpr int NPB_SHIFT = 9;            // 512 nodes per coarse bucket
static constexpr int NPB = 1 << NPB_SHIFT;
static constexpr int MAXC = 256;               // max coarse buckets (N <= 131072)
static constexpr int EPB = 2048;               // edges per part1 block

// ---------------------------------------------------------------- detect
__global__ __launch_bounds__(64) void k_detect(const unsigned long long* __restrict__ u,
                                               int* __restrict__ flag) {
    unsigned long long v = u[threadIdx.x];
    int hz = ((v >> 32) == 0ull) ? 1 : 0;
    int all64 = __all(hz);
    if (threadIdx.x == 0) flag[0] = all64;
}

__device__ __forceinline__ int load_idx(const void* ein, bool f64, long i) {
    return f64 ? (int)((const long long*)ein)[i] : ((const int*)ein)[i];
}

// ---------------------------------------------------------------- level-1 partition
// Bucket edges by dst>>9 into fixed-capacity spans of the packed array.
// Packed u64: [0:32) = w bits, [32:49) = src, [49:58) = dst & 511.
__global__ __launch_bounds__(256) void k_part1(const void* __restrict__ ein,
                                               const float* __restrict__ ew,
                                               const int* __restrict__ flag,
                                               int* __restrict__ gcur,
                                               unsigned long long* __restrict__ packed,
                                               int E, int NC, int cap) {
    __shared__ int lcnt[MAXC];
    __shared__ int lofs[MAXC];
    int tid = threadIdx.x;
    if (tid < NC) lcnt[tid] = 0;
    __syncthreads();
    bool f = flag[0];
    int base = blockIdx.x * EPB;
#pragma unroll
    for (int j = 0; j < EPB / 256; ++j) {
        int e = base + j * 256 + tid;
        if (e < E) {
            int d = load_idx(ein, f, (long)E + e);
            atomicAdd(&lcnt[d >> NPB_SHIFT], 1);
        }
    }
    __syncthreads();
    if (tid < NC) {
        int c = lcnt[tid];
        lofs[tid] = c ? atomicAdd(&gcur[tid], c) : 0;
        lcnt[tid] = 0;   // reuse as local cursor
    }
    __syncthreads();
#pragma unroll
    for (int j = 0; j < EPB / 256; ++j) {
        int e = base + j * 256 + tid;
        if (e < E) {
            int s = load_idx(ein, f, e);
            int d = load_idx(ein, f, (long)E + e);
            unsigned int wb = __float_as_uint(ew[e]);
            int b = d >> NPB_SHIFT;
            int pos = lofs[b] + atomicAdd(&lcnt[b], 1);
            if (pos < cap) {
                unsigned long long u = (unsigned long long)wb
                                     | ((unsigned long long)(unsigned)s << 32)
                                     | ((unsigned long long)(unsigned)(d & (NPB - 1)) << 49);
                packed[(long)b * cap + pos] = u;
            }
        }
    }
}

// ---------------------------------------------------------------- bucket-count scan
__global__ __launch_bounds__(256) void k_scanNC(const int* __restrict__ gcur,
                                                int* __restrict__ gbase,
                                                int* __restrict__ rp,
                                                int NC, int N, int E) {
    __shared__ int sm[256];
    int tid = threadIdx.x;
    int c = (tid < NC) ? gcur[tid] : 0;
    sm[tid] = c;
    __syncthreads();
    for (int off = 1; off < 256; off <<= 1) {
        int v = 0;
        if (tid >= off) v = sm[tid - off];
        __syncthreads();
        sm[tid] += v;
        __syncthreads();
    }
    if (tid < NC) gbase[tid] = sm[tid] - c;
    if (tid == 0) { gbase[NC] = E; rp[N] = E; }
}

// ---------------------------------------------------------------- per-bucket hist + scan
__global__ __launch_bounds__(256) void k_chist(const unsigned long long* __restrict__ packed,
                                               const int* __restrict__ gcur,
                                               const int* __restrict__ gbase,
                                               int* __restrict__ rp,
                                               float* __restrict__ dinv,
                                               int N, int cap) {
    __shared__ int   lc[NPB];
    __shared__ float ld[NPB];
    __shared__ int   sm[256];
    int b = blockIdx.x, tid = threadIdx.x;
#pragma unroll
    for (int i = tid; i < NPB; i += 256) { lc[i] = 0; ld[i] = 0.0f; }
    __syncthreads();
    int cnt = gcur[b];
    const unsigned long long* pk = packed + (long)b * cap;
    for (int p = tid; p < cnt; p += 256) {
        unsigned long long u = pk[p];
        int dl = (int)(u >> 49);
        atomicAdd(&lc[dl], 1);
        atomicAdd(&ld[dl], __uint_as_float((unsigned int)u));
    }
    __syncthreads();
    int c0 = lc[tid * 2], c1 = lc[tid * 2 + 1];
    int s = c0 + c1;
    sm[tid] = s;
    __syncthreads();
    for (int off = 1; off < 256; off <<= 1) {
        int v = 0;
        if (tid >= off) v = sm[tid - off];
        __syncthreads();
        sm[tid] += v;
        __syncthreads();
    }
    int excl = sm[tid] - s + gbase[b];
    int n0 = b << NPB_SHIFT;
    int node0 = n0 + tid * 2, node1 = node0 + 1;
    if (node0 < N) {
        rp[node0]   = excl;
        dinv[node0] = rsqrtf(ld[tid * 2] + 1.0f);
    }
    if (node1 < N) {
        rp[node1]   = excl + c0;
        dinv[node1] = rsqrtf(ld[tid * 2 + 1] + 1.0f);
    }
}

// ---------------------------------------------------------------- per-bucket CSR scatter
__global__ __launch_bounds__(256) void k_cscatter(const unsigned long long* __restrict__ packed,
                                                  const int* __restrict__ gcur,
                                                  const int* __restrict__ rp,
                                                  const float* __restrict__ dinv,
                                                  int* __restrict__ col,
                                                  float* __restrict__ val,
                                                  int N, int cap) {
    __shared__ int   cur[NPB];
    __shared__ float dd[NPB];
    int b = blockIdx.x, tid = threadIdx.x;
    int n0 = b << NPB_SHIFT;
#pragma unroll
    for (int i = tid; i < NPB; i += 256) {
        int node = n0 + i;
        cur[i] = (node < N) ? rp[node]   : 0;
        dd[i]  = (node < N) ? dinv[node] : 0.0f;
    }
    __syncthreads();
    int cnt = gcur[b];
    const unsigned long long* pk = packed + (long)b * cap;
    for (int p = tid; p < cnt; p += 256) {
        unsigned long long u = pk[p];
        int dl = (int)(u >> 49);
        int s  = (int)((u >> 32) & 0x1FFFF);
        float w = __uint_as_float((unsigned int)u);
        int pos = atomicAdd(&cur[dl], 1);
        col[pos] = s;
        val[pos] = dinv[s] * w * dd[dl];
    }
}

// ---------------------------------------------------------------- GEMM: [M,K]@[K,64]
template <int K>
__global__ __launch_bounds__(256) void k_gemm(const float* __restrict__ A,
                                              const float* __restrict__ W,
                                              float* __restrict__ C, int M) {
    __shared__ float As[64][68];
    __shared__ float Ws[64][64];
    int tid = threadIdx.x;
    int tx = tid & 15, ty = tid >> 4;
    int rb = blockIdx.x * 64;
    float acc[4][4] = {};
    for (int kc = 0; kc < K; kc += 64) {
        __syncthreads();
        for (int e = tid * 4; e < 64 * 64; e += 1024) {
            int r = e >> 6, k = e & 63;
            int gr = rb + r;
            float4 v = make_float4(0.f, 0.f, 0.f, 0.f);
            if (gr < M) v = *(const float4*)&A[(long)gr * K + kc + k];
            *(float4*)&As[r][k] = v;
        }
        for (int e = tid * 4; e < 64 * 64; e += 1024) {
            int r = e >> 6, k = e & 63;
            *(float4*)&Ws[r][k] = *(const float4*)&W[(long)(kc + r) * 64 + k];
        }
        __syncthreads();
#pragma unroll 16
        for (int k = 0; k < 64; ++k) {
            float a0 = As[ty * 4 + 0][k];
            float a1 = As[ty * 4 + 1][k];
            float a2 = As[ty * 4 + 2][k];
            float a3 = As[ty * 4 + 3][k];
            float4 b = *(float4*)&Ws[k][tx * 4];
            acc[0][0] = fmaf(a0, b.x, acc[0][0]); acc[0][1] = fmaf(a0, b.y, acc[0][1]);
            acc[0][2] = fmaf(a0, b.z, acc[0][2]); acc[0][3] = fmaf(a0, b.w, acc[0][3]);
            acc[1][0] = fmaf(a1, b.x, acc[1][0]); acc[1][1] = fmaf(a1, b.y, acc[1][1]);
            acc[1][2] = fmaf(a1, b.z, acc[1][2]); acc[1][3] = fmaf(a1, b.w, acc[1][3]);
            acc[2][0] = fmaf(a2, b.x, acc[2][0]); acc[2][1] = fmaf(a2, b.y, acc[2][1]);
            acc[2][2] = fmaf(a2, b.z, acc[2][2]); acc[2][3] = fmaf(a2, b.w, acc[2][3]);
            acc[3][0] = fmaf(a3, b.x, acc[3][0]); acc[3][1] = fmaf(a3, b.y, acc[3][1]);
            acc[3][2] = fmaf(a3, b.z, acc[3][2]); acc[3][3] = fmaf(a3, b.w, acc[3][3]);
        }
    }
#pragma unroll
    for (int j = 0; j < 4; ++j) {
        int gr = rb + ty * 4 + j;
        if (gr < M) {
            float4 v = make_float4(acc[j][0], acc[j][1], acc[j][2], acc[j][3]);
            *(float4*)&C[(long)gr * 64 + tx * 4] = v;
        }
    }
}

// ---------------------------------------------------------------- aggregation v3
// wave per node, split 4 edge-slots x 16 feature-lanes. Lane accumulates a
// float4 of features; gathers are dwordx4; one batch = 32 edges per wave,
// 8 independent gathers in flight per lane. Butterfly-reduce edge slots at
// the end (shfl_xor 16, 32), then add self-loop + bias, ReLU, store (es==0).
__global__ __launch_bounds__(256) void k_agg(const float* __restrict__ h,
                                             const int* __restrict__ rp,
                                             const int* __restrict__ col,
                                             const float* __restrict__ val,
                                             const float* __restrict__ dinv,
                                             const float* __restrict__ bias,
                                             float* __restrict__ out, int N) {
    int wid  = (blockIdx.x * 256 + threadIdx.x) >> 6;
    int lane = threadIdx.x & 63;
    int fg   = lane & 15;        // feature group -> features fg*4 .. fg*4+3
    int es   = lane >> 4;        // edge slot 0..3
    if (wid >= N) return;
    int e0 = rp[wid], e1 = rp[wid + 1];
    float4 acc = make_float4(0.f, 0.f, 0.f, 0.f);
    for (int base = e0 + es; base < e1; base += 32) {
        int   s[8];
        float wv[8];
#pragma unroll
        for (int j = 0; j < 8; ++j) {
            int e   = base + j * 4;
            int ok  = e < e1;
            int idx = ok ? e : e0;
            s[j]  = col[idx];
            wv[j] = ok ? val[idx] : 0.0f;
        }
        float4 hv[8];
#pragma unroll
        for (int j = 0; j < 8; ++j)
            hv[j] = *(const float4*)&h[(long)s[j] * 64 + fg * 4];
#pragma unroll
        for (int j = 0; j < 8; ++j) {
            acc.x = fmaf(wv[j], hv[j].x, acc.x);
            acc.y = fmaf(wv[j], hv[j].y, acc.y);
            acc.z = fmaf(wv[j], hv[j].z, acc.z);
            acc.w = fmaf(wv[j], hv[j].w, acc.w);
        }
    }
    // reduce the 4 edge slots (butterfly over lanemask 16, 32)
#pragma unroll
    for (int m = 16; m <= 32; m <<= 1) {
        acc.x += __shfl_xor(acc.x, m);
        acc.y += __shfl_xor(acc.y, m);
        acc.z += __shfl_xor(acc.z, m);
        acc.w += __shfl_xor(acc.w, m);
    }
    float di  = dinv[wid];
    float di2 = di * di;
    float4 hs = *(const float4*)&h[(long)wid * 64 + fg * 4];
    float4 bv = *(const float4*)&bias[fg * 4];
    acc.x = fmaf(hs.x, di2, acc.x + bv.x);
    acc.y = fmaf(hs.y, di2, acc.y + bv.y);
    acc.z = fmaf(hs.z, di2, acc.z + bv.z);
    acc.w = fmaf(hs.w, di2, acc.w + bv.w);
    if (es == 0) {
        float4 r = make_float4(fmaxf(acc.x, 0.f), fmaxf(acc.y, 0.f),
                               fmaxf(acc.z, 0.f), fmaxf(acc.w, 0.f));
        *(float4*)&out[(long)wid * 64 + fg * 4] = r;
    }
}

// ---------------------------------------------------------------- FC: [M,64]@[64,10]+b
__global__ __launch_bounds__(256) void k_fc(const float* __restrict__ h,
                                            const float* __restrict__ W,
                                            const float* __restrict__ b,
                                            float* __restrict__ out, int N) {
    __shared__ float Ws[64 * 10];
    __shared__ float bs[16];
    int tid = threadIdx.x;
    for (int e = tid; e < 64 * 10; e += 256) Ws[e] = W[e];
    if (tid < 10) bs[tid] = b[tid];
    __syncthreads();
    int i = blockIdx.x * 256 + tid;
    if (i >= N) return;
    float acc[10];
#pragma unroll
    for (int j = 0; j < 10; ++j) acc[j] = bs[j];
    const float4* row = (const float4*)&h[(long)i * 64];
#pragma unroll
    for (int c = 0; c < 16; ++c) {
        float4 a = row[c];
#pragma unroll
        for (int j = 0; j < 10; ++j) {
            acc[j] = fmaf(a.x, Ws[(4 * c + 0) * 10 + j], acc[j]);
            acc[j] = fmaf(a.y, Ws[(4 * c + 1) * 10 + j], acc[j]);
            acc[j] = fmaf(a.z, Ws[(4 * c + 2) * 10 + j], acc[j]);
            acc[j] = fmaf(a.w, Ws[(4 * c + 3) * 10 + j], acc[j]);
        }
    }
#pragma unroll
    for (int j = 0; j < 10; ++j) out[(long)i * 10 + j] = acc[j];
}

// ---------------------------------------------------------------- launch
extern "C" void kernel_launch(void* const* d_in, const int* in_sizes, int n_in,
                              void* d_out, int out_size, void* d_ws, size_t ws_size,
                              hipStream_t stream) {
    const float* x    = (const float*)d_in[0];
    const void*  eidx = d_in[1];
    const float* ew   = (const float*)d_in[2];
    const float* W1   = (const float*)d_in[3];
    const float* b1   = (const float*)d_in[4];
    const float* W2   = (const float*)d_in[5];
    const float* b2   = (const float*)d_in[6];
    const float* Wfc  = (const float*)d_in[7];
    const float* bfc  = (const float*)d_in[8];
    float* out = (float*)d_out;

    const int N  = in_sizes[0] / F_IN;            // 100000
    const int E  = in_sizes[2];                   // 1600000
    const int NC = (N + NPB - 1) >> NPB_SHIFT;    // 196 coarse buckets
    const int cap = E / NC + E / (2 * NC) + 1024; // ~1.6x mean + slack

    char* w = (char*)d_ws;
    size_t off = 0;
    auto alloc = [&](size_t bytes) {
        void* p = w + off;
        off += (bytes + 255) & ~(size_t)255;
        return p;
    };
    float* dinv  = (float*)alloc((size_t)N * 4);
    int*   rp    = (int*)alloc((size_t)(N + 1) * 4);
    int*   flag  = (int*)alloc(256);
    int*   gcur  = (int*)alloc((size_t)MAXC * 4);
    int*   gbase = (int*)alloc((size_t)(MAXC + 1) * 4);
    unsigned long long* packed =
        (unsigned long long*)alloc((size_t)NC * cap * 8);
    int*   col   = (int*)alloc((size_t)E * 4);
    float* val   = (float*)alloc((size_t)E * 4);
    float* h1    = (float*)alloc((size_t)N * F_H * 4);
    float* g     = (float*)alloc((size_t)N * F_H * 4);
    (void)ws_size;

    hipMemsetAsync(gcur, 0, (size_t)NC * 4, stream);

    const int PB = (E + EPB - 1) / EPB;   // 782 part1 blocks

    k_detect<<<1, 64, 0, stream>>>((const unsigned long long*)eidx, flag);
    k_part1<<<PB, 256, 0, stream>>>(eidx, ew, flag, gcur, packed, E, NC, cap);
    k_scanNC<<<1, 256, 0, stream>>>(gcur, gbase, rp, NC, N, E);
    k_chist<<<NC, 256, 0, stream>>>(packed, gcur, gbase, rp, dinv, N, cap);
    k_cscatter<<<NC, 256, 0, stream>>>(packed, gcur, rp, dinv, col, val, N, cap);

    const int GB = (N + 63) / 64;
    k_gemm<F_IN><<<GB, 256, 0, stream>>>(x, W1, h1, N);                 // h1 = x@W1
    k_agg<<<(N + 3) / 4, 256, 0, stream>>>(h1, rp, col, val, dinv, b1, g, N);
    k_gemm<F_H><<<GB, 256, 0, stream>>>(g, W2, h1, N);                  // h2pre = g@W2
    k_agg<<<(N + 3) / 4, 256, 0, stream>>>(h1, rp, col, val, dinv, b2, g, N);
    k_fc<<<(N + 255) / 256, 256, 0, stream>>>(g, Wfc, bfc, out, N);
}

// Round 6
// 241.827 us; speedup vs baseline: 2.6290x; 1.1166x over previous
//
#include <hip/hip_runtime.h>

static constexpr int F_IN  = 128;
static constexpr int F_H   = 64;
static constexpr int F_OUT = 10;

static constexpr int NPB_SHIFT = 9;            // 512 nodes per coarse bucket
static constexpr int NPB = 1 << NPB_SHIFT;
static constexpr int MAXC = 256;               // max coarse buckets (N <= 131072)
static constexpr int EPB = 2048;               // edges per part1 block

// bf16 helpers: rows of h are stored as bf16 (halves gather FETCH traffic;
// absmax budget 1.48e-2 >> quantization contribution ~2e-3).
__device__ __forceinline__ unsigned short f2bf(float f) {          // RNE
    unsigned u = __float_as_uint(f);
    return (unsigned short)((u + 0x7fff + ((u >> 16) & 1)) >> 16);
}
__device__ __forceinline__ float bf_lo(unsigned u) { return __uint_as_float(u << 16); }
__device__ __forceinline__ float bf_hi(unsigned u) { return __uint_as_float(u & 0xffff0000u); }

// ---------------------------------------------------------------- detect
__global__ __launch_bounds__(64) void k_detect(const unsigned long long* __restrict__ u,
                                               int* __restrict__ flag) {
    unsigned long long v = u[threadIdx.x];
    int hz = ((v >> 32) == 0ull) ? 1 : 0;
    int all64 = __all(hz);
    if (threadIdx.x == 0) flag[0] = all64;
}

__device__ __forceinline__ int load_idx(const void* ein, bool f64, long i) {
    return f64 ? (int)((const long long*)ein)[i] : ((const int*)ein)[i];
}

// ---------------------------------------------------------------- level-1 partition
// Packed u64: [0:32) = w bits, [32:49) = src, [49:58) = dst & 511.
__global__ __launch_bounds__(256) void k_part1(const void* __restrict__ ein,
                                               const float* __restrict__ ew,
                                               const int* __restrict__ flag,
                                               int* __restrict__ gcur,
                                               unsigned long long* __restrict__ packed,
                                               int E, int NC, int cap) {
    __shared__ int lcnt[MAXC];
    __shared__ int lofs[MAXC];
    int tid = threadIdx.x;
    if (tid < NC) lcnt[tid] = 0;
    __syncthreads();
    bool f = flag[0];
    int base = blockIdx.x * EPB;
#pragma unroll
    for (int j = 0; j < EPB / 256; ++j) {
        int e = base + j * 256 + tid;
        if (e < E) {
            int d = load_idx(ein, f, (long)E + e);
            atomicAdd(&lcnt[d >> NPB_SHIFT], 1);
        }
    }
    __syncthreads();
    if (tid < NC) {
        int c = lcnt[tid];
        lofs[tid] = c ? atomicAdd(&gcur[tid], c) : 0;
        lcnt[tid] = 0;   // reuse as local cursor
    }
    __syncthreads();
#pragma unroll
    for (int j = 0; j < EPB / 256; ++j) {
        int e = base + j * 256 + tid;
        if (e < E) {
            int s = load_idx(ein, f, e);
            int d = load_idx(ein, f, (long)E + e);
            unsigned int wb = __float_as_uint(ew[e]);
            int b = d >> NPB_SHIFT;
            int pos = lofs[b] + atomicAdd(&lcnt[b], 1);
            if (pos < cap) {
                unsigned long long u = (unsigned long long)wb
                                     | ((unsigned long long)(unsigned)s << 32)
                                     | ((unsigned long long)(unsigned)(d & (NPB - 1)) << 49);
                packed[(long)b * cap + pos] = u;
            }
        }
    }
}

// ---------------------------------------------------------------- bucket-count scan
__global__ __launch_bounds__(256) void k_scanNC(const int* __restrict__ gcur,
                                                int* __restrict__ gbase,
                                                int* __restrict__ rp,
                                                int NC, int N, int E) {
    __shared__ int sm[256];
    int tid = threadIdx.x;
    int c = (tid < NC) ? gcur[tid] : 0;
    sm[tid] = c;
    __syncthreads();
    for (int off = 1; off < 256; off <<= 1) {
        int v = 0;
        if (tid >= off) v = sm[tid - off];
        __syncthreads();
        sm[tid] += v;
        __syncthreads();
    }
    if (tid < NC) gbase[tid] = sm[tid] - c;
    if (tid == 0) { gbase[NC] = E; rp[N] = E; }
}

// ---------------------------------------------------------------- per-bucket hist + scan
__global__ __launch_bounds__(256) void k_chist(const unsigned long long* __restrict__ packed,
                                               const int* __restrict__ gcur,
                                               const int* __restrict__ gbase,
                                               int* __restrict__ rp,
                                               float* __restrict__ dinv,
                                               int N, int cap) {
    __shared__ int   lc[NPB];
    __shared__ float ld[NPB];
    __shared__ int   sm[256];
    int b = blockIdx.x, tid = threadIdx.x;
#pragma unroll
    for (int i = tid; i < NPB; i += 256) { lc[i] = 0; ld[i] = 0.0f; }
    __syncthreads();
    int cnt = gcur[b];
    const unsigned long long* pk = packed + (long)b * cap;
    for (int p = tid; p < cnt; p += 256) {
        unsigned long long u = pk[p];
        int dl = (int)(u >> 49);
        atomicAdd(&lc[dl], 1);
        atomicAdd(&ld[dl], __uint_as_float((unsigned int)u));
    }
    __syncthreads();
    int c0 = lc[tid * 2], c1 = lc[tid * 2 + 1];
    int s = c0 + c1;
    sm[tid] = s;
    __syncthreads();
    for (int off = 1; off < 256; off <<= 1) {
        int v = 0;
        if (tid >= off) v = sm[tid - off];
        __syncthreads();
        sm[tid] += v;
        __syncthreads();
    }
    int excl = sm[tid] - s + gbase[b];
    int n0 = b << NPB_SHIFT;
    int node0 = n0 + tid * 2, node1 = node0 + 1;
    if (node0 < N) {
        rp[node0]   = excl;
        dinv[node0] = rsqrtf(ld[tid * 2] + 1.0f);
    }
    if (node1 < N) {
        rp[node1]   = excl + c0;
        dinv[node1] = rsqrtf(ld[tid * 2 + 1] + 1.0f);
    }
}

// ---------------------------------------------------------------- per-bucket CSR scatter
// col holds PRE-SCALED byte offsets (src * 128 = bf16 row stride) so the
// aggregation gather needs no per-edge multiply.
__global__ __launch_bounds__(256) void k_cscatter(const unsigned long long* __restrict__ packed,
                                                  const int* __restrict__ gcur,
                                                  const int* __restrict__ rp,
                                                  const float* __restrict__ dinv,
                                                  int* __restrict__ col,
                                                  float* __restrict__ val,
                                                  int N, int cap) {
    __shared__ int   cur[NPB];
    __shared__ float dd[NPB];
    int b = blockIdx.x, tid = threadIdx.x;
    int n0 = b << NPB_SHIFT;
#pragma unroll
    for (int i = tid; i < NPB; i += 256) {
        int node = n0 + i;
        cur[i] = (node < N) ? rp[node]   : 0;
        dd[i]  = (node < N) ? dinv[node] : 0.0f;
    }
    __syncthreads();
    int cnt = gcur[b];
    const unsigned long long* pk = packed + (long)b * cap;
    for (int p = tid; p < cnt; p += 256) {
        unsigned long long u = pk[p];
        int dl = (int)(u >> 49);
        int s  = (int)((u >> 32) & 0x1FFFF);
        float w = __uint_as_float((unsigned int)u);
        int pos = atomicAdd(&cur[dl], 1);
        col[pos] = s << 7;                    // byte offset into bf16 h
        val[pos] = dinv[s] * w * dd[dl];
    }
}

// ---------------------------------------------------------------- GEMM: [M,K]@[K,64] -> bf16
template <int K>
__global__ __launch_bounds__(256) void k_gemm(const float* __restrict__ A,
                                              const float* __restrict__ W,
                                              unsigned short* __restrict__ Cb, int M) {
    __shared__ float As[64][68];
    __shared__ float Ws[64][64];
    int tid = threadIdx.x;
    int tx = tid & 15, ty = tid >> 4;
    int rb = blockIdx.x * 64;
    float acc[4][4] = {};
    for (int kc = 0; kc < K; kc += 64) {
        __syncthreads();
        for (int e = tid * 4; e < 64 * 64; e += 1024) {
            int r = e >> 6, k = e & 63;
            int gr = rb + r;
            float4 v = make_float4(0.f, 0.f, 0.f, 0.f);
            if (gr < M) v = *(const float4*)&A[(long)gr * K + kc + k];
            *(float4*)&As[r][k] = v;
        }
        for (int e = tid * 4; e < 64 * 64; e += 1024) {
            int r = e >> 6, k = e & 63;
            *(float4*)&Ws[r][k] = *(const float4*)&W[(long)(kc + r) * 64 + k];
        }
        __syncthreads();
#pragma unroll 16
        for (int k = 0; k < 64; ++k) {
            float a0 = As[ty * 4 + 0][k];
            float a1 = As[ty * 4 + 1][k];
            float a2 = As[ty * 4 + 2][k];
            float a3 = As[ty * 4 + 3][k];
            float4 b = *(float4*)&Ws[k][tx * 4];
            acc[0][0] = fmaf(a0, b.x, acc[0][0]); acc[0][1] = fmaf(a0, b.y, acc[0][1]);
            acc[0][2] = fmaf(a0, b.z, acc[0][2]); acc[0][3] = fmaf(a0, b.w, acc[0][3]);
            acc[1][0] = fmaf(a1, b.x, acc[1][0]); acc[1][1] = fmaf(a1, b.y, acc[1][1]);
            acc[1][2] = fmaf(a1, b.z, acc[1][2]); acc[1][3] = fmaf(a1, b.w, acc[1][3]);
            acc[2][0] = fmaf(a2, b.x, acc[2][0]); acc[2][1] = fmaf(a2, b.y, acc[2][1]);
            acc[2][2] = fmaf(a2, b.z, acc[2][2]); acc[2][3] = fmaf(a2, b.w, acc[2][3]);
            acc[3][0] = fmaf(a3, b.x, acc[3][0]); acc[3][1] = fmaf(a3, b.y, acc[3][1]);
            acc[3][2] = fmaf(a3, b.z, acc[3][2]); acc[3][3] = fmaf(a3, b.w, acc[3][3]);
        }
    }
#pragma unroll
    for (int j = 0; j < 4; ++j) {
        int gr = rb + ty * 4 + j;
        if (gr < M) {
            ushort4 v;
            v.x = f2bf(acc[j][0]); v.y = f2bf(acc[j][1]);
            v.z = f2bf(acc[j][2]); v.w = f2bf(acc[j][3]);
            *(ushort4*)&Cb[(long)gr * 64 + tx * 4] = v;
        }
    }
}

// ---------------------------------------------------------------- aggregation v4 (bf16 gather)
// wave per node: 16 feature-lanes (4 feats each) x 4 edge-slots. Gathers are
// uint2 (4 bf16), 8 independent per lane per batch (32 edges/wave/batch).
// col[] holds byte offsets. f32 accumulate; butterfly over slots; f32 out.
__global__ __launch_bounds__(256, 4) void k_agg(const unsigned short* __restrict__ hb,
                                                const int* __restrict__ rp,
                                                const int* __restrict__ col,
                                                const float* __restrict__ val,
                                                const float* __restrict__ dinv,
                                                const float* __restrict__ bias,
                                                float* __restrict__ out, int N) {
    int wid  = (blockIdx.x * 256 + threadIdx.x) >> 6;
    int lane = threadIdx.x & 63;
    int fg   = lane & 15;        // features fg*4 .. fg*4+3
    int es   = lane >> 4;        // edge slot 0..3
    if (wid >= N) return;
    const char* hbase = (const char*)hb;
    int e0 = rp[wid], e1 = rp[wid + 1];
    float a0 = 0.f, a1 = 0.f, a2 = 0.f, a3 = 0.f;
    for (int base = e0 + es; base < e1; base += 32) {
        int   off[8];
        float wv[8];
#pragma unroll
        for (int j = 0; j < 8; ++j) {
            int e   = base + j * 4;
            bool ok = e < e1;
            int idx = ok ? e : e0;
            off[j] = col[idx];
            wv[j]  = ok ? val[idx] : 0.0f;
        }
        uint2 hv[8];
#pragma unroll
        for (int j = 0; j < 8; ++j)
            hv[j] = *(const uint2*)(hbase + off[j] + fg * 8);
#pragma unroll
        for (int j = 0; j < 8; ++j) {
            a0 = fmaf(wv[j], bf_lo(hv[j].x), a0);
            a1 = fmaf(wv[j], bf_hi(hv[j].x), a1);
            a2 = fmaf(wv[j], bf_lo(hv[j].y), a2);
            a3 = fmaf(wv[j], bf_hi(hv[j].y), a3);
        }
    }
#pragma unroll
    for (int m = 16; m <= 32; m <<= 1) {
        a0 += __shfl_xor(a0, m);
        a1 += __shfl_xor(a1, m);
        a2 += __shfl_xor(a2, m);
        a3 += __shfl_xor(a3, m);
    }
    float di  = dinv[wid];
    float di2 = di * di;
    uint2 hs = *(const uint2*)(hbase + ((long)wid << 7) + fg * 8);
    float4 bv = *(const float4*)&bias[fg * 4];
    a0 = fmaf(bf_lo(hs.x), di2, a0 + bv.x);
    a1 = fmaf(bf_hi(hs.x), di2, a1 + bv.y);
    a2 = fmaf(bf_lo(hs.y), di2, a2 + bv.z);
    a3 = fmaf(bf_hi(hs.y), di2, a3 + bv.w);
    if (es == 0) {
        float4 r = make_float4(fmaxf(a0, 0.f), fmaxf(a1, 0.f),
                               fmaxf(a2, 0.f), fmaxf(a3, 0.f));
        *(float4*)&out[(long)wid * 64 + fg * 4] = r;
    }
}

// ---------------------------------------------------------------- FC: [M,64]@[64,10]+b
__global__ __launch_bounds__(256) void k_fc(const float* __restrict__ h,
                                            const float* __restrict__ W,
                                            const float* __restrict__ b,
                                            float* __restrict__ out, int N) {
    __shared__ float Ws[64 * 10];
    __shared__ float bs[16];
    int tid = threadIdx.x;
    for (int e = tid; e < 64 * 10; e += 256) Ws[e] = W[e];
    if (tid < 10) bs[tid] = b[tid];
    __syncthreads();
    int i = blockIdx.x * 256 + tid;
    if (i >= N) return;
    float acc[10];
#pragma unroll
    for (int j = 0; j < 10; ++j) acc[j] = bs[j];
    const float4* row = (const float4*)&h[(long)i * 64];
#pragma unroll
    for (int c = 0; c < 16; ++c) {
        float4 a = row[c];
#pragma unroll
        for (int j = 0; j < 10; ++j) {
            acc[j] = fmaf(a.x, Ws[(4 * c + 0) * 10 + j], acc[j]);
            acc[j] = fmaf(a.y, Ws[(4 * c + 1) * 10 + j], acc[j]);
            acc[j] = fmaf(a.z, Ws[(4 * c + 2) * 10 + j], acc[j]);
            acc[j] = fmaf(a.w, Ws[(4 * c + 3) * 10 + j], acc[j]);
        }
    }
#pragma unroll
    for (int j = 0; j < 10; ++j) out[(long)i * 10 + j] = acc[j];
}

// ---------------------------------------------------------------- launch
extern "C" void kernel_launch(void* const* d_in, const int* in_sizes, int n_in,
                              void* d_out, int out_size, void* d_ws, size_t ws_size,
                              hipStream_t stream) {
    const float* x    = (const float*)d_in[0];
    const void*  eidx = d_in[1];
    const float* ew   = (const float*)d_in[2];
    const float* W1   = (const float*)d_in[3];
    const float* b1   = (const float*)d_in[4];
    const float* W2   = (const float*)d_in[5];
    const float* b2   = (const float*)d_in[6];
    const float* Wfc  = (const float*)d_in[7];
    const float* bfc  = (const float*)d_in[8];
    float* out = (float*)d_out;

    const int N  = in_sizes[0] / F_IN;            // 100000
    const int E  = in_sizes[2];                   // 1600000
    const int NC = (N + NPB - 1) >> NPB_SHIFT;    // 196 coarse buckets
    const int cap = E / NC + E / (2 * NC) + 1024; // ~1.6x mean + slack

    char* w = (char*)d_ws;
    size_t off = 0;
    auto alloc = [&](size_t bytes) {
        void* p = w + off;
        off += (bytes + 255) & ~(size_t)255;
        return p;
    };
    float* dinv  = (float*)alloc((size_t)N * 4);
    int*   rp    = (int*)alloc((size_t)(N + 1) * 4);
    int*   flag  = (int*)alloc(256);
    int*   gcur  = (int*)alloc((size_t)MAXC * 4);
    int*   gbase = (int*)alloc((size_t)(MAXC + 1) * 4);
    unsigned long long* packed =
        (unsigned long long*)alloc((size_t)NC * cap * 8);
    int*   col   = (int*)alloc((size_t)E * 4);
    float* val   = (float*)alloc((size_t)E * 4);
    unsigned short* h1b = (unsigned short*)alloc((size_t)N * F_H * 2);
    unsigned short* h2b = (unsigned short*)alloc((size_t)N * F_H * 2);
    float* g1    = (float*)alloc((size_t)N * F_H * 4);
    float* g2    = (float*)alloc((size_t)N * F_H * 4);
    (void)ws_size;

    hipMemsetAsync(gcur, 0, (size_t)NC * 4, stream);

    const int PB = (E + EPB - 1) / EPB;   // 782 part1 blocks

    k_detect<<<1, 64, 0, stream>>>((const unsigned long long*)eidx, flag);
    k_part1<<<PB, 256, 0, stream>>>(eidx, ew, flag, gcur, packed, E, NC, cap);
    k_scanNC<<<1, 256, 0, stream>>>(gcur, gbase, rp, NC, N, E);
    k_chist<<<NC, 256, 0, stream>>>(packed, gcur, gbase, rp, dinv, N, cap);
    k_cscatter<<<NC, 256, 0, stream>>>(packed, gcur, rp, dinv, col, val, N, cap);

    const int GB = (N + 63) / 64;
    k_gemm<F_IN><<<GB, 256, 0, stream>>>(x, W1, h1b, N);                // h1 = bf16(x@W1)
    k_agg<<<(N + 3) / 4, 256, 0, stream>>>(h1b, rp, col, val, dinv, b1, g1, N);
    k_gemm<F_H><<<GB, 256, 0, stream>>>(g1, W2, h2b, N);                // h2 = bf16(g1@W2)
    k_agg<<<(N + 3) / 4, 256, 0, stream>>>(h2b, rp, col, val, dinv, b2, g2, N);
    k_fc<<<(N + 255) / 256, 256, 0, stream>>>(g2, Wfc, bfc, out, N);
}

// Round 7
// 228.141 us; speedup vs baseline: 2.7867x; 1.0600x over previous
//
#include <hip/hip_runtime.h>

static constexpr int F_IN  = 128;
static constexpr int F_H   = 64;
static constexpr int F_OUT = 10;

static constexpr int NPB_SHIFT = 9;            // 512 nodes per coarse bucket
static constexpr int NPB = 1 << NPB_SHIFT;
static constexpr int MAXC = 256;               // max coarse buckets (N <= 131072)
static constexpr int EPB = 2048;               // edges per part1 block

// bf16 helpers
__device__ __forceinline__ unsigned short f2bf(float f) {          // RNE
    unsigned u = __float_as_uint(f);
    return (unsigned short)((u + 0x7fff + ((u >> 16) & 1)) >> 16);
}
__device__ __forceinline__ float bf_lo(unsigned u) { return __uint_as_float(u << 16); }
__device__ __forceinline__ float bf_hi(unsigned u) { return __uint_as_float(u & 0xffff0000u); }

// ---------------------------------------------------------------- detect
__global__ __launch_bounds__(64) void k_detect(const unsigned long long* __restrict__ u,
                                               int* __restrict__ flag) {
    unsigned long long v = u[threadIdx.x];
    int hz = ((v >> 32) == 0ull) ? 1 : 0;
    int all64 = __all(hz);
    if (threadIdx.x == 0) flag[0] = all64;
}

__device__ __forceinline__ int load_idx(const void* ein, bool f64, long i) {
    return f64 ? (int)((const long long*)ein)[i] : ((const int*)ein)[i];
}

// ---------------------------------------------------------------- level-1 partition
// Packed u64: [0:32) = w bits, [32:49) = src, [49:58) = dst & 511.
__global__ __launch_bounds__(256) void k_part1(const void* __restrict__ ein,
                                               const float* __restrict__ ew,
                                               const int* __restrict__ flag,
                                               int* __restrict__ gcur,
                                               unsigned long long* __restrict__ packed,
                                               int E, int NC, int cap) {
    __shared__ int lcnt[MAXC];
    __shared__ int lofs[MAXC];
    int tid = threadIdx.x;
    if (tid < NC) lcnt[tid] = 0;
    __syncthreads();
    bool f = flag[0];
    int base = blockIdx.x * EPB;
#pragma unroll
    for (int j = 0; j < EPB / 256; ++j) {
        int e = base + j * 256 + tid;
        if (e < E) {
            int d = load_idx(ein, f, (long)E + e);
            atomicAdd(&lcnt[d >> NPB_SHIFT], 1);
        }
    }
    __syncthreads();
    if (tid < NC) {
        int c = lcnt[tid];
        lofs[tid] = c ? atomicAdd(&gcur[tid], c) : 0;
        lcnt[tid] = 0;   // reuse as local cursor
    }
    __syncthreads();
#pragma unroll
    for (int j = 0; j < EPB / 256; ++j) {
        int e = base + j * 256 + tid;
        if (e < E) {
            int s = load_idx(ein, f, e);
            int d = load_idx(ein, f, (long)E + e);
            unsigned int wb = __float_as_uint(ew[e]);
            int b = d >> NPB_SHIFT;
            int pos = lofs[b] + atomicAdd(&lcnt[b], 1);
            if (pos < cap) {
                unsigned long long u = (unsigned long long)wb
                                     | ((unsigned long long)(unsigned)s << 32)
                                     | ((unsigned long long)(unsigned)(d & (NPB - 1)) << 49);
                packed[(long)b * cap + pos] = u;
            }
        }
    }
}

// ---------------------------------------------------------------- per-bucket hist + padded scan
// One block per bucket: per-node cnt/deg hist (LDS atomics), PADDED (mult-16)
// local exclusive scan -> rp_local; writes bucket padded total to pbt[b];
// dinv = rsqrt(deg + 1).
__global__ __launch_bounds__(256) void k_chist(const unsigned long long* __restrict__ packed,
                                               const int* __restrict__ gcur,
                                               int* __restrict__ rp,
                                               int* __restrict__ pbt,
                                               float* __restrict__ dinv,
                                               int N, int cap) {
    __shared__ int   lc[NPB];
    __shared__ float ld[NPB];
    __shared__ int   sm[256];
    int b = blockIdx.x, tid = threadIdx.x;
#pragma unroll
    for (int i = tid; i < NPB; i += 256) { lc[i] = 0; ld[i] = 0.0f; }
    __syncthreads();
    int cnt = gcur[b];
    const unsigned long long* pk = packed + (long)b * cap;
    for (int p = tid; p < cnt; p += 256) {
        unsigned long long u = pk[p];
        int dl = (int)(u >> 49);
        atomicAdd(&lc[dl], 1);
        atomicAdd(&ld[dl], __uint_as_float((unsigned int)u));
    }
    __syncthreads();
    int c0 = lc[tid * 2], c1 = lc[tid * 2 + 1];
    int p0 = (c0 + 15) & ~15, p1 = (c1 + 15) & ~15;   // padded degs
    int s = p0 + p1;
    sm[tid] = s;
    __syncthreads();
    for (int off = 1; off < 256; off <<= 1) {
        int v = 0;
        if (tid >= off) v = sm[tid - off];
        __syncthreads();
        sm[tid] += v;
        __syncthreads();
    }
    int excl = sm[tid] - s;                            // local padded exclusive
    int n0 = b << NPB_SHIFT;
    int node0 = n0 + tid * 2, node1 = node0 + 1;
    if (node0 < N) {
        rp[node0]   = excl;
        dinv[node0] = rsqrtf(ld[tid * 2] + 1.0f);
    }
    if (node1 < N) {
        rp[node1]   = excl + p0;
        dinv[node1] = rsqrtf(ld[tid * 2 + 1] + 1.0f);
    }
    if (tid == 255) pbt[b] = sm[255];                  // bucket padded total
}

// ---------------------------------------------------------------- bucket padded scan
__global__ __launch_bounds__(256) void k_scanP(const int* __restrict__ pbt,
                                               int* __restrict__ pbase,
                                               int* __restrict__ rp, int NC, int N) {
    __shared__ int sm[256];
    int tid = threadIdx.x;
    int c = (tid < NC) ? pbt[tid] : 0;
    sm[tid] = c;
    __syncthreads();
    for (int off = 1; off < 256; off <<= 1) {
        int v = 0;
        if (tid >= off) v = sm[tid - off];
        __syncthreads();
        sm[tid] += v;
        __syncthreads();
    }
    if (tid < NC) pbase[tid] = sm[tid] - c;
    if (tid == 255) rp[N] = sm[255];                   // absolute padded total
}

// ---------------------------------------------------------------- rp -> absolute
__global__ __launch_bounds__(256) void k_rpfix(int* __restrict__ rp,
                                               const int* __restrict__ pbase, int N) {
    int i = blockIdx.x * 256 + threadIdx.x;
    if (i < N) rp[i] += pbase[i >> NPB_SHIFT];
}

// ---------------------------------------------------------------- per-bucket CSR scatter
// Emits fused records rec = {src byte offset, normalized weight} into the
// node's padded span, then zero-fills the pad gap (off=0,w=0 -> harmless).
__global__ __launch_bounds__(256) void k_cscatter(const unsigned long long* __restrict__ packed,
                                                  const int* __restrict__ gcur,
                                                  const int* __restrict__ rp,
                                                  const float* __restrict__ dinv,
                                                  uint2* __restrict__ recs,
                                                  int N, int cap) {
    __shared__ int   cur[NPB];
    __shared__ float dd[NPB];
    int b = blockIdx.x, tid = threadIdx.x;
    int n0 = b << NPB_SHIFT;
#pragma unroll
    for (int i = tid; i < NPB; i += 256) {
        int node = n0 + i;
        cur[i] = (node < N) ? rp[node]   : 0;
        dd[i]  = (node < N) ? dinv[node] : 0.0f;
    }
    __syncthreads();
    int cnt = gcur[b];
    const unsigned long long* pk = packed + (long)b * cap;
    for (int p = tid; p < cnt; p += 256) {
        unsigned long long u = pk[p];
        int dl = (int)(u >> 49);
        int s  = (int)((u >> 32) & 0x1FFFF);
        float w = __uint_as_float((unsigned int)u);
        int pos = atomicAdd(&cur[dl], 1);
        uint2 r;
        r.x = (unsigned)(s << 7);             // byte offset into bf16 h
        r.y = __float_as_uint(dinv[s] * w * dd[dl]);
        recs[pos] = r;
    }
    __syncthreads();
    for (int i = tid; i < NPB; i += 256) {    // zero-fill pad gaps
        int node = n0 + i;
        if (node < N) {
            int end = rp[node + 1];
            for (int p = cur[i]; p < end; ++p) recs[p] = make_uint2(0u, 0u);
        }
    }
}

// ---------------------------------------------------------------- GEMM: [M,K]@[K,64] -> bf16
template <int K>
__global__ __launch_bounds__(256) void k_gemm(const float* __restrict__ A,
                                              const float* __restrict__ W,
                                              unsigned short* __restrict__ Cb, int M) {
    __shared__ float As[64][68];
    __shared__ float Ws[64][64];
    int tid = threadIdx.x;
    int tx = tid & 15, ty = tid >> 4;
    int rb = blockIdx.x * 64;
    float acc[4][4] = {};
    for (int kc = 0; kc < K; kc += 64) {
        __syncthreads();
        for (int e = tid * 4; e < 64 * 64; e += 1024) {
            int r = e >> 6, k = e & 63;
            int gr = rb + r;
            float4 v = make_float4(0.f, 0.f, 0.f, 0.f);
            if (gr < M) v = *(const float4*)&A[(long)gr * K + kc + k];
            *(float4*)&As[r][k] = v;
        }
        for (int e = tid * 4; e < 64 * 64; e += 1024) {
            int r = e >> 6, k = e & 63;
            *(float4*)&Ws[r][k] = *(const float4*)&W[(long)(kc + r) * 64 + k];
        }
        __syncthreads();
#pragma unroll 16
        for (int k = 0; k < 64; ++k) {
            float a0 = As[ty * 4 + 0][k];
            float a1 = As[ty * 4 + 1][k];
            float a2 = As[ty * 4 + 2][k];
            float a3 = As[ty * 4 + 3][k];
            float4 b = *(float4*)&Ws[k][tx * 4];
            acc[0][0] = fmaf(a0, b.x, acc[0][0]); acc[0][1] = fmaf(a0, b.y, acc[0][1]);
            acc[0][2] = fmaf(a0, b.z, acc[0][2]); acc[0][3] = fmaf(a0, b.w, acc[0][3]);
            acc[1][0] = fmaf(a1, b.x, acc[1][0]); acc[1][1] = fmaf(a1, b.y, acc[1][1]);
            acc[1][2] = fmaf(a1, b.z, acc[1][2]); acc[1][3] = fmaf(a1, b.w, acc[1][3]);
            acc[2][0] = fmaf(a2, b.x, acc[2][0]); acc[2][1] = fmaf(a2, b.y, acc[2][1]);
            acc[2][2] = fmaf(a2, b.z, acc[2][2]); acc[2][3] = fmaf(a2, b.w, acc[2][3]);
            acc[3][0] = fmaf(a3, b.x, acc[3][0]); acc[3][1] = fmaf(a3, b.y, acc[3][1]);
            acc[3][2] = fmaf(a3, b.z, acc[3][2]); acc[3][3] = fmaf(a3, b.w, acc[3][3]);
        }
    }
#pragma unroll
    for (int j = 0; j < 4; ++j) {
        int gr = rb + ty * 4 + j;
        if (gr < M) {
            ushort4 v;
            v.x = f2bf(acc[j][0]); v.y = f2bf(acc[j][1]);
            v.z = f2bf(acc[j][2]); v.w = f2bf(acc[j][3]);
            *(ushort4*)&Cb[(long)gr * 64 + tx * 4] = v;
        }
    }
}

// ---------------------------------------------------------------- aggregation v5
// wave per node: 16 feature-lanes x 4 edge-slots over PADDED fused records.
// Block of 16 recs, slot es owns recs [es*4, es*4+4): two dwordx4 loads per
// batch, 4 uint2 bf16 gathers, zero compares in the hot loop.
__global__ __launch_bounds__(256, 4) void k_agg(const unsigned short* __restrict__ hb,
                                                const int* __restrict__ rp,
                                                const uint2* __restrict__ recs,
                                                const float* __restrict__ dinv,
                                                const float* __restrict__ bias,
                                                float* __restrict__ out, int N) {
    int wid  = (blockIdx.x * 256 + threadIdx.x) >> 6;
    int lane = threadIdx.x & 63;
    int fg   = lane & 15;        // features fg*4 .. fg*4+3
    int es   = lane >> 4;        // edge slot 0..3
    if (wid >= N) return;
    int fg8 = fg * 8;
    const char* hbase = (const char*)hb;
    int p0 = rp[wid], p1 = rp[wid + 1];
    float a0 = 0.f, a1 = 0.f, a2 = 0.f, a3 = 0.f;
    for (int pb = p0 + es * 4; pb < p1; pb += 16) {
        uint4 r01 = *(const uint4*)&recs[pb];        // recs pb, pb+1
        uint4 r23 = *(const uint4*)&recs[pb + 2];    // recs pb+2, pb+3
        uint2 h0 = *(const uint2*)(hbase + r01.x + fg8);
        uint2 h1 = *(const uint2*)(hbase + r01.z + fg8);
        uint2 h2 = *(const uint2*)(hbase + r23.x + fg8);
        uint2 h3 = *(const uint2*)(hbase + r23.z + fg8);
        float w0 = __uint_as_float(r01.y), w1 = __uint_as_float(r01.w);
        float w2 = __uint_as_float(r23.y), w3 = __uint_as_float(r23.w);
        a0 = fmaf(w0, bf_lo(h0.x), a0); a1 = fmaf(w0, bf_hi(h0.x), a1);
        a2 = fmaf(w0, bf_lo(h0.y), a2); a3 = fmaf(w0, bf_hi(h0.y), a3);
        a0 = fmaf(w1, bf_lo(h1.x), a0); a1 = fmaf(w1, bf_hi(h1.x), a1);
        a2 = fmaf(w1, bf_lo(h1.y), a2); a3 = fmaf(w1, bf_hi(h1.y), a3);
        a0 = fmaf(w2, bf_lo(h2.x), a0); a1 = fmaf(w2, bf_hi(h2.x), a1);
        a2 = fmaf(w2, bf_lo(h2.y), a2); a3 = fmaf(w2, bf_hi(h2.y), a3);
        a0 = fmaf(w3, bf_lo(h3.x), a0); a1 = fmaf(w3, bf_hi(h3.x), a1);
        a2 = fmaf(w3, bf_lo(h3.y), a2); a3 = fmaf(w3, bf_hi(h3.y), a3);
    }
#pragma unroll
    for (int m = 16; m <= 32; m <<= 1) {
        a0 += __shfl_xor(a0, m);
        a1 += __shfl_xor(a1, m);
        a2 += __shfl_xor(a2, m);
        a3 += __shfl_xor(a3, m);
    }
    float di  = dinv[wid];
    float di2 = di * di;
    uint2 hs = *(const uint2*)(hbase + ((long)wid << 7) + fg8);
    float4 bv = *(const float4*)&bias[fg * 4];
    a0 = fmaf(bf_lo(hs.x), di2, a0 + bv.x);
    a1 = fmaf(bf_hi(hs.x), di2, a1 + bv.y);
    a2 = fmaf(bf_lo(hs.y), di2, a2 + bv.z);
    a3 = fmaf(bf_hi(hs.y), di2, a3 + bv.w);
    if (es == 0) {
        float4 r = make_float4(fmaxf(a0, 0.f), fmaxf(a1, 0.f),
                               fmaxf(a2, 0.f), fmaxf(a3, 0.f));
        *(float4*)&out[(long)wid * 64 + fg * 4] = r;
    }
}

// ---------------------------------------------------------------- FC: [M,64]@[64,10]+b
__global__ __launch_bounds__(256) void k_fc(const float* __restrict__ h,
                                            const float* __restrict__ W,
                                            const float* __restrict__ b,
                                            float* __restrict__ out, int N) {
    __shared__ float Ws[64 * 10];
    __shared__ float bs[16];
    int tid = threadIdx.x;
    for (int e = tid; e < 64 * 10; e += 256) Ws[e] = W[e];
    if (tid < 10) bs[tid] = b[tid];
    __syncthreads();
    int i = blockIdx.x * 256 + tid;
    if (i >= N) return;
    float acc[10];
#pragma unroll
    for (int j = 0; j < 10; ++j) acc[j] = bs[j];
    const float4* row = (const float4*)&h[(long)i * 64];
#pragma unroll
    for (int c = 0; c < 16; ++c) {
        float4 a = row[c];
#pragma unroll
        for (int j = 0; j < 10; ++j) {
            acc[j] = fmaf(a.x, Ws[(4 * c + 0) * 10 + j], acc[j]);
            acc[j] = fmaf(a.y, Ws[(4 * c + 1) * 10 + j], acc[j]);
            acc[j] = fmaf(a.z, Ws[(4 * c + 2) * 10 + j], acc[j]);
            acc[j] = fmaf(a.w, Ws[(4 * c + 3) * 10 + j], acc[j]);
        }
    }
#pragma unroll
    for (int j = 0; j < 10; ++j) out[(long)i * 10 + j] = acc[j];
}

// ---------------------------------------------------------------- launch
extern "C" void kernel_launch(void* const* d_in, const int* in_sizes, int n_in,
                              void* d_out, int out_size, void* d_ws, size_t ws_size,
                              hipStream_t stream) {
    const float* x    = (const float*)d_in[0];
    const void*  eidx = d_in[1];
    const float* ew   = (const float*)d_in[2];
    const float* W1   = (const float*)d_in[3];
    const float* b1   = (const float*)d_in[4];
    const float* W2   = (const float*)d_in[5];
    const float* b2   = (const float*)d_in[6];
    const float* Wfc  = (const float*)d_in[7];
    const float* bfc  = (const float*)d_in[8];
    float* out = (float*)d_out;

    const int N  = in_sizes[0] / F_IN;            // 100000
    const int E  = in_sizes[2];                   // 1600000
    const int NC = (N + NPB - 1) >> NPB_SHIFT;    // 196 coarse buckets
    const int cap = E / NC + E / (8 * NC) + 1024; // mean + ~25 sigma slack

    char* w = (char*)d_ws;
    size_t off = 0;
    auto alloc = [&](size_t bytes) {
        void* p = w + off;
        off += (bytes + 255) & ~(size_t)255;
        return p;
    };
    float* dinv  = (float*)alloc((size_t)N * 4);
    int*   rp    = (int*)alloc((size_t)(N + 1) * 4);
    int*   flag  = (int*)alloc(256);
    int*   gcur  = (int*)alloc((size_t)MAXC * 4);
    int*   pbt   = (int*)alloc((size_t)MAXC * 4);
    int*   pbase = (int*)alloc((size_t)MAXC * 4);
    unsigned long long* packed =
        (unsigned long long*)alloc((size_t)NC * cap * 8);
    uint2* recs  = (uint2*)alloc(((size_t)E + 15u * (size_t)N + 64) * 8);
    unsigned short* h1b = (unsigned short*)alloc((size_t)N * F_H * 2);
    float* g1    = (float*)alloc((size_t)N * F_H * 4);
    unsigned short* h2b = h1b;   // alias: h1b dead after agg1
    float* g2    = g1;           // alias: g1 dead after gemm2
    (void)ws_size;

    hipMemsetAsync(gcur, 0, (size_t)NC * 4, stream);

    const int PB = (E + EPB - 1) / EPB;   // part1 blocks

    k_detect<<<1, 64, 0, stream>>>((const unsigned long long*)eidx, flag);
    k_part1<<<PB, 256, 0, stream>>>(eidx, ew, flag, gcur, packed, E, NC, cap);
    k_chist<<<NC, 256, 0, stream>>>(packed, gcur, rp, pbt, dinv, N, cap);
    k_scanP<<<1, 256, 0, stream>>>(pbt, pbase, rp, NC, N);
    k_rpfix<<<(N + 255) / 256, 256, 0, stream>>>(rp, pbase, N);
    k_cscatter<<<NC, 256, 0, stream>>>(packed, gcur, rp, dinv, recs, N, cap);

    const int GB = (N + 63) / 64;
    k_gemm<F_IN><<<GB, 256, 0, stream>>>(x, W1, h1b, N);                // h1 = bf16(x@W1)
    k_agg<<<(N + 3) / 4, 256, 0, stream>>>(h1b, rp, recs, dinv, b1, g1, N);
    k_gemm<F_H><<<GB, 256, 0, stream>>>(g1, W2, h2b, N);                // h2 = bf16(g1@W2)
    k_agg<<<(N + 3) / 4, 256, 0, stream>>>(h2b, rp, recs, dinv, b2, g2, N);
    k_fc<<<(N + 255) / 256, 256, 0, stream>>>(g2, Wfc, bfc, out, N);
}

// Round 8
// 220.548 us; speedup vs baseline: 2.8827x; 1.0344x over previous
//
#include <hip/hip_runtime.h>

static constexpr int F_IN  = 128;
static constexpr int F_H   = 64;
static constexpr int F_OUT = 10;

static constexpr int NPB_SHIFT = 9;            // 512 nodes per coarse bucket
static constexpr int NPB = 1 << NPB_SHIFT;
static constexpr int MAXC = 256;               // max coarse buckets (N <= 131072)
static constexpr int EPB = 2048;               // edges per part1 block

// bf16 helpers
__device__ __forceinline__ unsigned short f2bf(float f) {          // RNE
    unsigned u = __float_as_uint(f);
    return (unsigned short)((u + 0x7fff + ((u >> 16) & 1)) >> 16);
}
__device__ __forceinline__ float bf_lo(unsigned u) { return __uint_as_float(u << 16); }
__device__ __forceinline__ float bf_hi(unsigned u) { return __uint_as_float(u & 0xffff0000u); }

// ---------------------------------------------------------------- detect
__global__ __launch_bounds__(64) void k_detect(const unsigned long long* __restrict__ u,
                                               int* __restrict__ flag) {
    unsigned long long v = u[threadIdx.x];
    int hz = ((v >> 32) == 0ull) ? 1 : 0;
    int all64 = __all(hz);
    if (threadIdx.x == 0) flag[0] = all64;
}

__device__ __forceinline__ int load_idx(const void* ein, bool f64, long i) {
    return f64 ? (int)((const long long*)ein)[i] : ((const int*)ein)[i];
}

// ---------------------------------------------------------------- level-1 partition
// Packed u64: [0:32) = w bits, [32:49) = src, [49:58) = dst & 511.
__global__ __launch_bounds__(256) void k_part1(const void* __restrict__ ein,
                                               const float* __restrict__ ew,
                                               const int* __restrict__ flag,
                                               int* __restrict__ gcur,
                                               unsigned long long* __restrict__ packed,
                                               int E, int NC, int cap) {
    __shared__ int lcnt[MAXC];
    __shared__ int lofs[MAXC];
    int tid = threadIdx.x;
    if (tid < NC) lcnt[tid] = 0;
    __syncthreads();
    bool f = flag[0];
    int base = blockIdx.x * EPB;
#pragma unroll
    for (int j = 0; j < EPB / 256; ++j) {
        int e = base + j * 256 + tid;
        if (e < E) {
            int d = load_idx(ein, f, (long)E + e);
            atomicAdd(&lcnt[d >> NPB_SHIFT], 1);
        }
    }
    __syncthreads();
    if (tid < NC) {
        int c = lcnt[tid];
        lofs[tid] = c ? atomicAdd(&gcur[tid], c) : 0;
        lcnt[tid] = 0;   // reuse as local cursor
    }
    __syncthreads();
#pragma unroll
    for (int j = 0; j < EPB / 256; ++j) {
        int e = base + j * 256 + tid;
        if (e < E) {
            int s = load_idx(ein, f, e);
            int d = load_idx(ein, f, (long)E + e);
            unsigned int wb = __float_as_uint(ew[e]);
            int b = d >> NPB_SHIFT;
            int pos = lofs[b] + atomicAdd(&lcnt[b], 1);
            if (pos < cap) {
                unsigned long long u = (unsigned long long)wb
                                     | ((unsigned long long)(unsigned)s << 32)
                                     | ((unsigned long long)(unsigned)(d & (NPB - 1)) << 49);
                packed[(long)b * cap + pos] = u;
            }
        }
    }
}

// ---------------------------------------------------------------- per-bucket hist + padded scan
__global__ __launch_bounds__(256) void k_chist(const unsigned long long* __restrict__ packed,
                                               const int* __restrict__ gcur,
                                               int* __restrict__ rp,
                                               int* __restrict__ pbt,
                                               float* __restrict__ dinv,
                                               int N, int cap) {
    __shared__ int   lc[NPB];
    __shared__ float ld[NPB];
    __shared__ int   sm[256];
    int b = blockIdx.x, tid = threadIdx.x;
#pragma unroll
    for (int i = tid; i < NPB; i += 256) { lc[i] = 0; ld[i] = 0.0f; }
    __syncthreads();
    int cnt = gcur[b];
    const unsigned long long* pk = packed + (long)b * cap;
    for (int p = tid; p < cnt; p += 256) {
        unsigned long long u = pk[p];
        int dl = (int)(u >> 49);
        atomicAdd(&lc[dl], 1);
        atomicAdd(&ld[dl], __uint_as_float((unsigned int)u));
    }
    __syncthreads();
    int c0 = lc[tid * 2], c1 = lc[tid * 2 + 1];
    int p0 = (c0 + 15) & ~15, p1 = (c1 + 15) & ~15;   // padded degs
    int s = p0 + p1;
    sm[tid] = s;
    __syncthreads();
    for (int off = 1; off < 256; off <<= 1) {
        int v = 0;
        if (tid >= off) v = sm[tid - off];
        __syncthreads();
        sm[tid] += v;
        __syncthreads();
    }
    int excl = sm[tid] - s;                            // local padded exclusive
    int n0 = b << NPB_SHIFT;
    int node0 = n0 + tid * 2, node1 = node0 + 1;
    if (node0 < N) {
        rp[node0]   = excl;
        dinv[node0] = rsqrtf(ld[tid * 2] + 1.0f);
    }
    if (node1 < N) {
        rp[node1]   = excl + p0;
        dinv[node1] = rsqrtf(ld[tid * 2 + 1] + 1.0f);
    }
    if (tid == 255) pbt[b] = sm[255];                  // bucket padded total
}

// ---------------------------------------------------------------- bucket padded scan
__global__ __launch_bounds__(256) void k_scanP(const int* __restrict__ pbt,
                                               int* __restrict__ pbase,
                                               int* __restrict__ rp, int NC, int N) {
    __shared__ int sm[256];
    int tid = threadIdx.x;
    int c = (tid < NC) ? pbt[tid] : 0;
    sm[tid] = c;
    __syncthreads();
    for (int off = 1; off < 256; off <<= 1) {
        int v = 0;
        if (tid >= off) v = sm[tid - off];
        __syncthreads();
        sm[tid] += v;
        __syncthreads();
    }
    if (tid < NC) pbase[tid] = sm[tid] - c;
    if (tid == 255) rp[N] = sm[255];                   // absolute padded total
}

// ---------------------------------------------------------------- rp -> absolute
__global__ __launch_bounds__(256) void k_rpfix(int* __restrict__ rp,
                                               const int* __restrict__ pbase, int N) {
    int i = blockIdx.x * 256 + threadIdx.x;
    if (i < N) rp[i] += pbase[i >> NPB_SHIFT];
}

// ---------------------------------------------------------------- per-bucket CSR scatter
__global__ __launch_bounds__(256) void k_cscatter(const unsigned long long* __restrict__ packed,
                                                  const int* __restrict__ gcur,
                                                  const int* __restrict__ rp,
                                                  const float* __restrict__ dinv,
                                                  uint2* __restrict__ recs,
                                                  int N, int cap) {
    __shared__ int   cur[NPB];
    __shared__ float dd[NPB];
    int b = blockIdx.x, tid = threadIdx.x;
    int n0 = b << NPB_SHIFT;
#pragma unroll
    for (int i = tid; i < NPB; i += 256) {
        int node = n0 + i;
        cur[i] = (node < N) ? rp[node]   : 0;
        dd[i]  = (node < N) ? dinv[node] : 0.0f;
    }
    __syncthreads();
    int cnt = gcur[b];
    const unsigned long long* pk = packed + (long)b * cap;
    for (int p = tid; p < cnt; p += 256) {
        unsigned long long u = pk[p];
        int dl = (int)(u >> 49);
        int s  = (int)((u >> 32) & 0x1FFFF);
        float w = __uint_as_float((unsigned int)u);
        int pos = atomicAdd(&cur[dl], 1);
        uint2 r;
        r.x = (unsigned)(s << 7);             // byte offset into bf16 h
        r.y = __float_as_uint(dinv[s] * w * dd[dl]);
        recs[pos] = r;
    }
    __syncthreads();
    for (int i = tid; i < NPB; i += 256) {    // zero-fill pad gaps
        int node = n0 + i;
        if (node < N) {
            int end = rp[node + 1];
            for (int p = cur[i]; p < end; ++p) recs[p] = make_uint2(0u, 0u);
        }
    }
}

// ---------------------------------------------------------------- GEMM v2: [M,K]@[K,64] -> bf16
// 128x64 tile, 256 threads (16x16), 8x4 outputs/thread, K chunked by 32.
// All LDS reads are b128: per 4-k granule 12 x ds_read_b128 feed 128 FMAs.
// A-tile granules XOR-swizzled by row-group so a wave's 4 row-groups hit
// disjoint bank quads (conflict-free broadcast).
template <int K>
__global__ __launch_bounds__(256) void k_gemm(const float* __restrict__ A,
                                              const float* __restrict__ W,
                                              unsigned short* __restrict__ Cb, int M) {
    __shared__ float As[128][32];   // 16 KB, granule-swizzled
    __shared__ float Ws[32][64];    // 8 KB
    int tid = threadIdx.x;
    int tx = tid & 15;              // col group: cols tx*4 .. tx*4+3
    int ty = tid >> 4;              // row group: rows ty*8 .. ty*8+7
    int rb = blockIdx.x * 128;
    float acc[8][4] = {};
    for (int kc = 0; kc < K; kc += 32) {
        __syncthreads();   // protect previous iteration's LDS reads
#pragma unroll
        for (int i = 0; i < 4; ++i) {          // stage A: 1024 float4
            int e = tid + i * 256;
            int r = e >> 3, g = e & 7;
            int gr = rb + r;
            float4 v = make_float4(0.f, 0.f, 0.f, 0.f);
            if (gr < M) v = *(const float4*)&A[(long)gr * K + kc + g * 4];
            int gs = g ^ ((r >> 3) & 7);
            *(float4*)&As[r][gs * 4] = v;
        }
#pragma unroll
        for (int i = 0; i < 2; ++i) {          // stage W: 512 float4
            int e = tid + i * 256;
            int k = e >> 4, n4 = e & 15;
            *(float4*)&Ws[k][n4 * 4] = *(const float4*)&W[(long)(kc + k) * 64 + n4 * 4];
        }
        __syncthreads();
#pragma unroll
        for (int g = 0; g < 8; ++g) {          // 4 k's per granule
            float4 b0 = *(const float4*)&Ws[g * 4 + 0][tx * 4];
            float4 b1 = *(const float4*)&Ws[g * 4 + 1][tx * 4];
            float4 b2 = *(const float4*)&Ws[g * 4 + 2][tx * 4];
            float4 b3 = *(const float4*)&Ws[g * 4 + 3][tx * 4];
            int gs = (g ^ (ty & 7)) * 4;       // r>>3 == ty for all 8 rows
#pragma unroll
            for (int rr = 0; rr < 8; ++rr) {
                float4 a = *(const float4*)&As[ty * 8 + rr][gs];
                acc[rr][0] = fmaf(a.x, b0.x, acc[rr][0]);
                acc[rr][1] = fmaf(a.x, b0.y, acc[rr][1]);
                acc[rr][2] = fmaf(a.x, b0.z, acc[rr][2]);
                acc[rr][3] = fmaf(a.x, b0.w, acc[rr][3]);
                acc[rr][0] = fmaf(a.y, b1.x, acc[rr][0]);
                acc[rr][1] = fmaf(a.y, b1.y, acc[rr][1]);
                acc[rr][2] = fmaf(a.y, b1.z, acc[rr][2]);
                acc[rr][3] = fmaf(a.y, b1.w, acc[rr][3]);
                acc[rr][0] = fmaf(a.z, b2.x, acc[rr][0]);
                acc[rr][1] = fmaf(a.z, b2.y, acc[rr][1]);
                acc[rr][2] = fmaf(a.z, b2.z, acc[rr][2]);
                acc[rr][3] = fmaf(a.z, b2.w, acc[rr][3]);
                acc[rr][0] = fmaf(a.w, b3.x, acc[rr][0]);
                acc[rr][1] = fmaf(a.w, b3.y, acc[rr][1]);
                acc[rr][2] = fmaf(a.w, b3.z, acc[rr][2]);
                acc[rr][3] = fmaf(a.w, b3.w, acc[rr][3]);
            }
        }
    }
#pragma unroll
    for (int rr = 0; rr < 8; ++rr) {
        int gr = rb + ty * 8 + rr;
        if (gr < M) {
            ushort4 v;
            v.x = f2bf(acc[rr][0]); v.y = f2bf(acc[rr][1]);
            v.z = f2bf(acc[rr][2]); v.w = f2bf(acc[rr][3]);
            *(ushort4*)&Cb[(long)gr * 64 + tx * 4] = v;
        }
    }
}

// ---------------------------------------------------------------- aggregation v5
__global__ __launch_bounds__(256, 4) void k_agg(const unsigned short* __restrict__ hb,
                                                const int* __restrict__ rp,
                                                const uint2* __restrict__ recs,
                                                const float* __restrict__ dinv,
                                                const float* __restrict__ bias,
                                                float* __restrict__ out, int N) {
    int wid  = (blockIdx.x * 256 + threadIdx.x) >> 6;
    int lane = threadIdx.x & 63;
    int fg   = lane & 15;        // features fg*4 .. fg*4+3
    int es   = lane >> 4;        // edge slot 0..3
    if (wid >= N) return;
    int fg8 = fg * 8;
    const char* hbase = (const char*)hb;
    int p0 = rp[wid], p1 = rp[wid + 1];
    float a0 = 0.f, a1 = 0.f, a2 = 0.f, a3 = 0.f;
    for (int pb = p0 + es * 4; pb < p1; pb += 16) {
        uint4 r01 = *(const uint4*)&recs[pb];        // recs pb, pb+1
        uint4 r23 = *(const uint4*)&recs[pb + 2];    // recs pb+2, pb+3
        uint2 h0 = *(const uint2*)(hbase + r01.x + fg8);
        uint2 h1 = *(const uint2*)(hbase + r01.z + fg8);
        uint2 h2 = *(const uint2*)(hbase + r23.x + fg8);
        uint2 h3 = *(const uint2*)(hbase + r23.z + fg8);
        float w0 = __uint_as_float(r01.y), w1 = __uint_as_float(r01.w);
        float w2 = __uint_as_float(r23.y), w3 = __uint_as_float(r23.w);
        a0 = fmaf(w0, bf_lo(h0.x), a0); a1 = fmaf(w0, bf_hi(h0.x), a1);
        a2 = fmaf(w0, bf_lo(h0.y), a2); a3 = fmaf(w0, bf_hi(h0.y), a3);
        a0 = fmaf(w1, bf_lo(h1.x), a0); a1 = fmaf(w1, bf_hi(h1.x), a1);
        a2 = fmaf(w1, bf_lo(h1.y), a2); a3 = fmaf(w1, bf_hi(h1.y), a3);
        a0 = fmaf(w2, bf_lo(h2.x), a0); a1 = fmaf(w2, bf_hi(h2.x), a1);
        a2 = fmaf(w2, bf_lo(h2.y), a2); a3 = fmaf(w2, bf_hi(h2.y), a3);
        a0 = fmaf(w3, bf_lo(h3.x), a0); a1 = fmaf(w3, bf_hi(h3.x), a1);
        a2 = fmaf(w3, bf_lo(h3.y), a2); a3 = fmaf(w3, bf_hi(h3.y), a3);
    }
#pragma unroll
    for (int m = 16; m <= 32; m <<= 1) {
        a0 += __shfl_xor(a0, m);
        a1 += __shfl_xor(a1, m);
        a2 += __shfl_xor(a2, m);
        a3 += __shfl_xor(a3, m);
    }
    float di  = dinv[wid];
    float di2 = di * di;
    uint2 hs = *(const uint2*)(hbase + ((long)wid << 7) + fg8);
    float4 bv = *(const float4*)&bias[fg * 4];
    a0 = fmaf(bf_lo(hs.x), di2, a0 + bv.x);
    a1 = fmaf(bf_hi(hs.x), di2, a1 + bv.y);
    a2 = fmaf(bf_lo(hs.y), di2, a2 + bv.z);
    a3 = fmaf(bf_hi(hs.y), di2, a3 + bv.w);
    if (es == 0) {
        float4 r = make_float4(fmaxf(a0, 0.f), fmaxf(a1, 0.f),
                               fmaxf(a2, 0.f), fmaxf(a3, 0.f));
        *(float4*)&out[(long)wid * 64 + fg * 4] = r;
    }
}

// ---------------------------------------------------------------- FC: [M,64]@[64,10]+b
__global__ __launch_bounds__(256) void k_fc(const float* __restrict__ h,
                                            const float* __restrict__ W,
                                            const float* __restrict__ b,
                                            float* __restrict__ out, int N) {
    __shared__ float Ws[64 * 10];
    __shared__ float bs[16];
    int tid = threadIdx.x;
    for (int e = tid; e < 64 * 10; e += 256) Ws[e] = W[e];
    if (tid < 10) bs[tid] = b[tid];
    __syncthreads();
    int i = blockIdx.x * 256 + tid;
    if (i >= N) return;
    float acc[10];
#pragma unroll
    for (int j = 0; j < 10; ++j) acc[j] = bs[j];
    const float4* row = (const float4*)&h[(long)i * 64];
#pragma unroll
    for (int c = 0; c < 16; ++c) {
        float4 a = row[c];
#pragma unroll
        for (int j = 0; j < 10; ++j) {
            acc[j] = fmaf(a.x, Ws[(4 * c + 0) * 10 + j], acc[j]);
            acc[j] = fmaf(a.y, Ws[(4 * c + 1) * 10 + j], acc[j]);
            acc[j] = fmaf(a.z, Ws[(4 * c + 2) * 10 + j], acc[j]);
            acc[j] = fmaf(a.w, Ws[(4 * c + 3) * 10 + j], acc[j]);
        }
    }
#pragma unroll
    for (int j = 0; j < 10; ++j) out[(long)i * 10 + j] = acc[j];
}

// ---------------------------------------------------------------- launch
extern "C" void kernel_launch(void* const* d_in, const int* in_sizes, int n_in,
                              void* d_out, int out_size, void* d_ws, size_t ws_size,
                              hipStream_t stream) {
    const float* x    = (const float*)d_in[0];
    const void*  eidx = d_in[1];
    const float* ew   = (const float*)d_in[2];
    const float* W1   = (const float*)d_in[3];
    const float* b1   = (const float*)d_in[4];
    const float* W2   = (const float*)d_in[5];
    const float* b2   = (const float*)d_in[6];
    const float* Wfc  = (const float*)d_in[7];
    const float* bfc  = (const float*)d_in[8];
    float* out = (float*)d_out;

    const int N  = in_sizes[0] / F_IN;            // 100000
    const int E  = in_sizes[2];                   // 1600000
    const int NC = (N + NPB - 1) >> NPB_SHIFT;    // 196 coarse buckets
    const int cap = E / NC + E / (8 * NC) + 1024; // mean + slack

    char* w = (char*)d_ws;
    size_t off = 0;
    auto alloc = [&](size_t bytes) {
        void* p = w + off;
        off += (bytes + 255) & ~(size_t)255;
        return p;
    };
    float* dinv  = (float*)alloc((size_t)N * 4);
    int*   rp    = (int*)alloc((size_t)(N + 1) * 4);
    int*   flag  = (int*)alloc(256);
    int*   gcur  = (int*)alloc((size_t)MAXC * 4);
    int*   pbt   = (int*)alloc((size_t)MAXC * 4);
    int*   pbase = (int*)alloc((size_t)MAXC * 4);
    unsigned long long* packed =
        (unsigned long long*)alloc((size_t)NC * cap * 8);
    uint2* recs  = (uint2*)alloc(((size_t)E + 15u * (size_t)N + 64) * 8);
    unsigned short* h1b = (unsigned short*)alloc((size_t)N * F_H * 2);
    float* g1    = (float*)alloc((size_t)N * F_H * 4);
    unsigned short* h2b = h1b;   // alias: h1b dead after agg1
    float* g2    = g1;           // alias: g1 dead after gemm2
    (void)ws_size;

    hipMemsetAsync(gcur, 0, (size_t)NC * 4, stream);

    const int PB = (E + EPB - 1) / EPB;   // part1 blocks

    k_detect<<<1, 64, 0, stream>>>((const unsigned long long*)eidx, flag);
    k_part1<<<PB, 256, 0, stream>>>(eidx, ew, flag, gcur, packed, E, NC, cap);
    k_chist<<<NC, 256, 0, stream>>>(packed, gcur, rp, pbt, dinv, N, cap);
    k_scanP<<<1, 256, 0, stream>>>(pbt, pbase, rp, NC, N);
    k_rpfix<<<(N + 255) / 256, 256, 0, stream>>>(rp, pbase, N);
    k_cscatter<<<NC, 256, 0, stream>>>(packed, gcur, rp, dinv, recs, N, cap);

    const int GB = (N + 127) / 128;
    k_gemm<F_IN><<<GB, 256, 0, stream>>>(x, W1, h1b, N);                // h1 = bf16(x@W1)
    k_agg<<<(N + 3) / 4, 256, 0, stream>>>(h1b, rp, recs, dinv, b1, g1, N);
    k_gemm<F_H><<<GB, 256, 0, stream>>>(g1, W2, h2b, N);                // h2 = bf16(g1@W2)
    k_agg<<<(N + 3) / 4, 256, 0, stream>>>(h2b, rp, recs, dinv, b2, g2, N);
    k_fc<<<(N + 255) / 256, 256, 0, stream>>>(g2, Wfc, bfc, out, N);
}